// Round 16
// baseline (573.422 us; speedup 1.0000x reference)
//
#include <hip/hip_runtime.h>

typedef unsigned short u16;
typedef unsigned int u32;
typedef __attribute__((ext_vector_type(8))) short short8;
typedef __attribute__((ext_vector_type(4))) float f32x4;

constexpr int Bn = 8, Cn = 384, Hn = 64, Wn = 64, Tn = Hn * Wn, Mn = Bn * Tn, HIDn = 1536;
constexpr size_t MB = 1024 * 1024;
constexpr int NCH = 64, LCH = Tn / NCH;      // 64 chunks x 64 steps
constexpr int NLANE = Bn * NCH * Cn;         // state lanes (per channel)
constexpr int CV = 8;                        // conv outputs per chunk (along w)

__device__ __forceinline__ u16 f2bf(float f) {
  unsigned u = __builtin_bit_cast(unsigned, f);
  unsigned r = (u + 0x7fffu + ((u >> 16) & 1u)) >> 16;
  return (u16)r;
}

__device__ __forceinline__ float bf2f(u16 h) {
  return __builtin_bit_cast(float, (unsigned)h << 16);
}

__device__ __forceinline__ float2 bf2x(u32 w) {
  float2 r;
  r.x = bf2f((u16)(w & 0xffffu));
  r.y = bf2f((u16)(w >> 16));
  return r;
}

__device__ __forceinline__ u32 f2bx(float a, float b) {
  return (u32)f2bf(a) | ((u32)f2bf(b) << 16);
}

__device__ __forceinline__ void gload16(const u16* g, u16* l) {
  __builtin_amdgcn_global_load_lds(
      (const __attribute__((address_space(1))) unsigned int*)(g),
      (__attribute__((address_space(3))) unsigned int*)(l), 16, 0, 0);
}

// ---------------- transpose x [B,C,T] fp32 -> tok [B,T,C] bf16 ----------------
__global__ void k_transpose_in(const float* __restrict__ x, u16* __restrict__ tok) {
  __shared__ float tile[32][33];
  int b = blockIdx.z, t0 = blockIdx.x * 32, c0 = blockIdx.y * 32;
  int tt = threadIdx.x % 32, cc = threadIdx.x / 32;
  const float* xp = x + ((size_t)b * Cn + c0) * Tn + t0;
  for (int i = 0; i < 32; i += 8) tile[cc + i][tt] = xp[(size_t)(cc + i) * Tn + tt];
  __syncthreads();
  int cw = threadIdx.x % 32, tw = threadIdx.x / 32;
  u16* op = tok + ((size_t)b * Tn + t0) * Cn + c0;
  for (int i = 0; i < 32; i += 8) op[(size_t)(tw + i) * Cn + cw] = f2bf(tile[cw][tw + i]);
}

// ---------------- one-shot weight prep: bf16 converts + effective 5x5 + sumw -------------
__global__ void k_prep(const float* __restrict__ wk, const float* __restrict__ wv,
                       const float* __restrict__ wr, const float* __restrict__ wo,
                       const float* __restrict__ fwk, const float* __restrict__ fwr,
                       const float* __restrict__ fwv,
                       const float* __restrict__ aA, const float* __restrict__ w1A,
                       const float* __restrict__ w3A, const float* __restrict__ w5A,
                       const float* __restrict__ aF, const float* __restrict__ w1F,
                       const float* __restrict__ w3F, const float* __restrict__ w5F,
                       u16* __restrict__ wkb, u16* __restrict__ wvb, u16* __restrict__ wrb,
                       u16* __restrict__ wob, u16* __restrict__ fwkb, u16* __restrict__ fwrb,
                       u16* __restrict__ fwvb, float* __restrict__ weff,
                       float* __restrict__ sumw) {
  const int CC = Cn * Cn, CH = Cn * HIDn;
  int i = blockIdx.x * 256 + threadIdx.x;
  if (i < 4 * CC) {
    int seg = i / CC, j = i % CC;
    if (seg == 0) wkb[j] = f2bf(wk[j]);
    else if (seg == 1) wvb[j] = f2bf(wv[j]);
    else if (seg == 2) wrb[j] = f2bf(wr[j]);
    else wob[j] = f2bf(wo[j]);
    return;
  }
  i -= 4 * CC;
  if (i < CH) { fwkb[i] = f2bf(fwk[i]); return; }
  i -= CH;
  if (i < CC) { fwrb[i] = f2bf(fwr[i]); return; }
  i -= CC;
  if (i < CH) { fwvb[i] = f2bf(fwv[i]); return; }
  i -= CH;
  if (i < 2 * Cn * 25) {
    int set = i / (Cn * 25), rem = i % (Cn * 25), c = rem / 25, ij = rem % 25;
    int ki = ij / 5, kj = ij % 5;
    const float* a = set ? aF : aA;
    const float* w1 = set ? w1F : w1A;
    const float* w3 = set ? w3F : w3A;
    const float* w5 = set ? w5F : w5A;
    float v = a[3] * w5[c * 25 + ij];
    if (ki >= 1 && ki <= 3 && kj >= 1 && kj <= 3) v += a[2] * w3[c * 9 + (ki - 1) * 3 + (kj - 1)];
    if (ki == 2 && kj == 2) v += a[1] * w1[c] + a[0];
    weff[(set * 25 + ij) * Cn + c] = v;
    return;
  }
  i -= 2 * Cn * 25;
  if (i < 2 * Cn) {
    int set = i / Cn, c = i % Cn;
    const float* a = set ? aF : aA;
    const float* w1 = set ? w1F : w1A;
    const float* w3 = set ? w3F : w3A;
    const float* w5 = set ? w5F : w5A;
    float s = 0.f;
    for (int ij = 0; ij < 25; ij++) {
      int ki = ij / 5, kj = ij % 5;
      float v = a[3] * w5[c * 25 + ij];
      if (ki >= 1 && ki <= 3 && kj >= 1 && kj <= 3)
        v += a[2] * w3[c * 9 + (ki - 1) * 3 + (kj - 1)];
      if (ki == 2 && kj == 2) v += a[1] * w1[c] + a[0];
      s += v;
    }
    sumw[i] = s;
  }
}

// ---------------- fused LN: stats + write normalized x as bf16 (bf16 in) ----------------
__global__ void k_lnnorm(const u16* __restrict__ tok, u16* __restrict__ xs) {
  int token = blockIdx.x * 4 + (threadIdx.x >> 6);
  int lane = threadIdx.x & 63;
  const u32* p = (const u32*)(tok + (size_t)token * Cn);
  float v[6];
  float s = 0.f, s2 = 0.f;
#pragma unroll
  for (int j = 0; j < 3; j++) {
    float2 f = bf2x(p[lane + j * 64]);
    v[2 * j] = f.x; v[2 * j + 1] = f.y;
    s += f.x + f.y;
    s2 += f.x * f.x + f.y * f.y;
  }
  for (int off = 32; off; off >>= 1) { s += __shfl_xor(s, off); s2 += __shfl_xor(s2, off); }
  float m = s * (1.0f / Cn);
  float r = rsqrtf(s2 * (1.0f / Cn) - m * m + 1e-5f);
  u32* op = (u32*)(xs + (size_t)token * Cn);
#pragma unroll
  for (int j = 0; j < 3; j++)
    op[lane + j * 64] = f2bx((v[2 * j] - m) * r, (v[2 * j + 1] - m) * r);
}

// ---------------- 5x5 depthwise conv on normalized x (bf16 in/out) ----------------
__global__ __launch_bounds__(384) void k_conv(const u16* __restrict__ xs,
                                              const float* __restrict__ g,
                                              const float* __restrict__ bb,
                                              const float* __restrict__ weff,
                                              const float* __restrict__ sumw,
                                              u16* __restrict__ out) {
  int c = threadIdx.x;
  int h = blockIdx.x, b = blockIdx.y;
  float gc = g[c], bc = bb[c], s0 = sumw[c];
  float wv[25];
#pragma unroll
  for (int i = 0; i < 25; i++) wv[i] = weff[i * Cn + c];
  const u16* base = xs + (size_t)b * Tn * Cn + c;
  u16* orow = out + ((size_t)b * Tn + (size_t)h * Wn) * Cn + c;
  bool hOK = (h >= 2 && h <= Hn - 3);
  for (int w0 = 0; w0 < Wn; w0 += CV) {
    float acc[CV];
#pragma unroll
    for (int v = 0; v < CV; v++) acc[v] = 0.f;
    if (hOK && w0 != 0 && w0 != Wn - CV) {
#pragma unroll
      for (int ki = 0; ki < 5; ki++) {
        int rowt = (h + ki - 2) * Wn + w0 - 2;
#pragma unroll
        for (int jj = 0; jj < CV + 4; jj++) {
          float y = bf2f(base[(size_t)(rowt + jj) * Cn]);
#pragma unroll
          for (int v = 0; v < CV; v++) {
            int kj = jj - v;
            if (kj >= 0 && kj < 5) acc[v] = fmaf(y, wv[ki * 5 + kj], acc[v]);
          }
        }
      }
      u16* op = orow + (size_t)w0 * Cn;
#pragma unroll
      for (int v = 0; v < CV; v++) op[(size_t)v * Cn] = f2bf(gc * acc[v] + bc * s0);
    } else {
      float sw[CV];
#pragma unroll
      for (int v = 0; v < CV; v++) sw[v] = 0.f;
#pragma unroll
      for (int ki = 0; ki < 5; ki++) {
        int hh = h + ki - 2;
        if ((unsigned)hh >= (unsigned)Hn) continue;
#pragma unroll
        for (int jj = 0; jj < CV + 4; jj++) {
          int ww = w0 + jj - 2;
          if ((unsigned)ww >= (unsigned)Wn) continue;
          float y = bf2f(base[(size_t)(hh * Wn + ww) * Cn]);
#pragma unroll
          for (int v = 0; v < CV; v++) {
            int kj = jj - v;
            if (kj >= 0 && kj < 5) {
              float wt = wv[ki * 5 + kj];
              acc[v] = fmaf(y, wt, acc[v]);
              sw[v] += wt;
            }
          }
        }
      }
      u16* op = orow + (size_t)w0 * Cn;
#pragma unroll
      for (int v = 0; v < CV; v++) op[(size_t)v * Cn] = f2bf(gc * acc[v] + bc * sw[v]);
    }
  }
}

// ---- bf16 GEMM: 256x128 tile, 512 thr, BK=32, XOR swizzle, XCD remap ----
// 3-buffer pipeline with COUNTED vmcnt. Non-temporal output stores (protect A's L2 residency).
// MODE 3: tokH += gamma*val (bf16 in place, stride N)
// MODE 4: plain bf16 -> o1 (stride N)
// MODE 5: fused QKV: seg0->o1, seg1->o2, seg2->sigmoid->o3 (each stride 384)
// MODE 6: fused FFN: seg0->relu^2->o1 (stride 1536), seg1->sigmoid->o2 (stride 384)
template <int MODE>
__global__ __launch_bounds__(512) void k_gemm(const u16* __restrict__ A,
                                              const u16* __restrict__ Wt,
                                              u16* __restrict__ o1, u16* __restrict__ o2,
                                              u16* __restrict__ o3,
                                              u16* __restrict__ tokH,
                                              const float* __restrict__ gamma, int K, int N) {
  __shared__ u16 lds_a[3][256 * 32];
  __shared__ u16 lds_b[3][128 * 32];
  int tid = threadIdx.x;
  int id = blockIdx.y * gridDim.x + blockIdx.x;
  int xcd = id & 7, q = id >> 3;
  int gx8 = gridDim.x >> 3;                  // gridDim.x == 128 -> 16
  int bm = ((q % gx8) * 8 + xcd) * 256;
  int bn = (q / gx8) * 128;
  int wave = tid >> 6, lane = tid & 63;
  int wm = (wave >> 1) * 64, wn = (wave & 1) * 64;
  int lr = lane & 15, kg = lane >> 4;

  f32x4 acc[4][4];
#pragma unroll
  for (int i = 0; i < 4; i++)
#pragma unroll
    for (int j = 0; j < 4; j++) acc[i][j] = f32x4{0.f, 0.f, 0.f, 0.f};

  int r0 = tid >> 2;           // 0..127
  int fslot = tid & 3;
  int row2 = r0 + 128;
  int kgrA0 = fslot ^ ((r0 >> 1) & 3);
  int kgrA1 = fslot ^ ((row2 >> 1) & 3);
  const u16* gA0 = A + (size_t)(bm + r0) * K + kgrA0 * 8;
  const u16* gA1 = A + (size_t)(bm + row2) * K + kgrA1 * 8;
  const u16* gB0 = Wt + (size_t)(bn + r0) * K + kgrA0 * 8;
  int nk = K >> 5;

  gload16(gA0, &lds_a[0][tid * 8]);
  gload16(gA1, &lds_a[0][(tid + 512) * 8]);
  gload16(gB0, &lds_b[0][tid * 8]);
  gload16(gA0 + 32, &lds_a[1][tid * 8]);
  gload16(gA1 + 32, &lds_a[1][(tid + 512) * 8]);
  gload16(gB0 + 32, &lds_b[1][tid * 8]);

  for (int t = 0; t < nk; ++t) {
    int cur = t % 3;
    if (t + 2 < nk) {
      int k0 = (t + 2) << 5;
      int nb = (t + 2) % 3;
      gload16(gA0 + k0, &lds_a[nb][tid * 8]);
      gload16(gA1 + k0, &lds_a[nb][(tid + 512) * 8]);
      gload16(gB0 + k0, &lds_b[nb][tid * 8]);
      asm volatile("s_waitcnt vmcnt(6)" ::: "memory");
    } else if (t + 1 < nk) {
      asm volatile("s_waitcnt vmcnt(3)" ::: "memory");
    } else {
      asm volatile("s_waitcnt vmcnt(0)" ::: "memory");
    }
    __builtin_amdgcn_s_barrier();
    const u16* la = lds_a[cur];
    const u16* lb = lds_b[cur];
    short8 af[4], bfr[4];
#pragma unroll
    for (int mi = 0; mi < 4; mi++) {
      int row = wm + mi * 16 + lr;
      af[mi] = *(const short8*)&la[row * 32 + (kg ^ ((row >> 1) & 3)) * 8];
    }
#pragma unroll
    for (int ni = 0; ni < 4; ni++) {
      int row = wn + ni * 16 + lr;
      bfr[ni] = *(const short8*)&lb[row * 32 + (kg ^ ((row >> 1) & 3)) * 8];
    }
#pragma unroll
    for (int mi = 0; mi < 4; mi++)
#pragma unroll
      for (int ni = 0; ni < 4; ni++)
        acc[mi][ni] = __builtin_amdgcn_mfma_f32_16x16x32_bf16(af[mi], bfr[ni], acc[mi][ni], 0, 0, 0);
    __builtin_amdgcn_s_barrier();
  }

  int seg = 0;
  if (MODE == 5) seg = bn / 384;
  if (MODE == 6) seg = (bn >= 1536) ? 1 : 0;

#pragma unroll
  for (int mi = 0; mi < 4; mi++)
#pragma unroll
    for (int ni = 0; ni < 4; ni++) {
#pragma unroll
      for (int r = 0; r < 4; r++) {
        int gr = bm + wm + mi * 16 + kg * 4 + r;
        int gc = bn + wn + ni * 16 + lr;
        float v = acc[mi][ni][r];
        if (MODE == 3) {
          size_t idx = (size_t)gr * N + gc;
          tokH[idx] = f2bf(bf2f(tokH[idx]) + gamma[gc] * v);
        } else if (MODE == 4) {
          __builtin_nontemporal_store(f2bf(v), &o1[(size_t)gr * N + gc]);
        } else if (MODE == 5) {
          int col = gc - seg * 384;
          size_t idx = (size_t)gr * 384 + col;
          if (seg == 0) __builtin_nontemporal_store(f2bf(v), &o1[idx]);
          else if (seg == 1) __builtin_nontemporal_store(f2bf(v), &o2[idx]);
          else __builtin_nontemporal_store(f2bf(1.0f / (1.0f + __expf(-v))), &o3[idx]);
        } else if (MODE == 6) {
          if (seg == 0) {
            float tpos = fmaxf(v, 0.0f);
            __builtin_nontemporal_store(f2bf(tpos * tpos), &o1[(size_t)gr * 1536 + gc]);
          } else {
            __builtin_nontemporal_store(f2bf(1.0f / (1.0f + __expf(-v))),
                                        &o2[(size_t)gr * 384 + (gc - 1536)]);
          }
        }
      }
    }
}

// ---------------- chunked WKV scan (bf16 k/v packed u32, 2 channels/thread) ----------------
__global__ void k_scanA(const u32* __restrict__ k, const u32* __restrict__ v,
                        const float* __restrict__ decay, int dir,
                        float* __restrict__ SP, float* __restrict__ SQ, float* __restrict__ SO) {
  int gid = blockIdx.x * 256 + threadIdx.x;   // over Bn*NCH*192
  int cp = gid % 192;
  int ch = (gid / 192) % NCH;
  int b = gid / (192 * NCH);
  int c = cp * 2;
  float w0 = decay[dir * Cn + c] * (1.0f / Tn);
  float w1 = decay[dir * Cn + c + 1] * (1.0f / Tn);
  size_t be = dir ? ((size_t)b * Tn + ch) * Cn + c : ((size_t)b * Tn + (size_t)ch * LCH) * Cn + c;
  size_t base = be >> 1;
  size_t stride = (dir ? (size_t)Wn * Cn : (size_t)Cn) >> 1;
  const u32* kp = k + base;
  const u32* vp = v + base;
  float p0 = 0.f, q0 = 0.f, o0 = -1e30f, p1 = 0.f, q1 = 0.f, o1 = -1e30f;
  float2 kt = bf2x(kp[0]), vt = bf2x(vp[0]);
  for (int i = 0; i < LCH; i++) {
    float2 kn = {0.f, 0.f}, vn = {0.f, 0.f};
    if (i + 1 < LCH) { kn = bf2x(kp[stride * (i + 1)]); vn = bf2x(vp[stride * (i + 1)]); }
    float no = fmaxf(w0 + o0, kt.x);
    float Aa = __expf(w0 + o0 - no), Bb = __expf(kt.x - no);
    p0 = Aa * p0 + Bb * vt.x; q0 = Aa * q0 + Bb; o0 = no;
    no = fmaxf(w1 + o1, kt.y);
    Aa = __expf(w1 + o1 - no); Bb = __expf(kt.y - no);
    p1 = Aa * p1 + Bb * vt.y; q1 = Aa * q1 + Bb; o1 = no;
    kt = kn; vt = vn;
  }
  size_t sidx = ((size_t)b * NCH + ch) * Cn + c;
  SP[sidx] = p0; SP[sidx + 1] = p1;
  SQ[sidx] = q0; SQ[sidx + 1] = q1;
  SO[sidx] = o0; SO[sidx + 1] = o1;
}

__global__ void k_scanB(const float* __restrict__ decay, int dir,
                        float* __restrict__ SP, float* __restrict__ SQ, float* __restrict__ SO) {
  int gid = blockIdx.x * 256 + threadIdx.x;  // B*C
  int c = gid % Cn, b = gid / Cn;
  float wL = decay[dir * Cn + c] * (1.0f / Tn) * LCH;
  float p = 0.f, q = 0.f, o = -1e30f;
  size_t idx = (size_t)b * NCH * Cn + c;
  float lp = SP[idx], lq = SQ[idx], lo = SO[idx];
  for (int ch = 0; ch < NCH; ch++) {
    float np_ = 0.f, nq_ = 0.f, no_ = 0.f;
    if (ch + 1 < NCH) { np_ = SP[idx + Cn]; nq_ = SQ[idx + Cn]; no_ = SO[idx + Cn]; }
    SP[idx] = p; SQ[idx] = q; SO[idx] = o;
    float o1 = o + wL;
    float no = fmaxf(o1, lo);
    float e1 = __expf(o1 - no), e2 = __expf(lo - no);
    p = p * e1 + lp * e2;
    q = q * e1 + lq * e2;
    o = no;
    lp = np_; lq = nq_; lo = no_;
    idx += Cn;
  }
}

// Phase C: replay chunk. dir0: y -> v (in place). dir1: abf = bf16(r*y) (fused).
__global__ void k_scanC(const u32* __restrict__ k, u32* __restrict__ v,
                        const u32* __restrict__ rh, u32* __restrict__ abf,
                        const float* __restrict__ decay, const float* __restrict__ first, int dir,
                        const float* __restrict__ SP, const float* __restrict__ SQ,
                        const float* __restrict__ SO) {
  int gid = blockIdx.x * 256 + threadIdx.x;
  int cp = gid % 192;
  int ch = (gid / 192) % NCH;
  int b = gid / (192 * NCH);
  int c = cp * 2;
  float w0 = decay[dir * Cn + c] * (1.0f / Tn);
  float w1 = decay[dir * Cn + c + 1] * (1.0f / Tn);
  float u0 = first[dir * Cn + c] * (1.0f / Tn);
  float u1 = first[dir * Cn + c + 1] * (1.0f / Tn);
  size_t be = dir ? ((size_t)b * Tn + ch) * Cn + c : ((size_t)b * Tn + (size_t)ch * LCH) * Cn + c;
  size_t base = be >> 1;
  size_t stride = (dir ? (size_t)Wn * Cn : (size_t)Cn) >> 1;
  const u32* kp = k + base;
  u32* vp = v + base;
  size_t sidx = ((size_t)b * NCH + ch) * Cn + c;
  float p0 = SP[sidx], q0 = SQ[sidx], o0 = SO[sidx];
  float p1 = SP[sidx + 1], q1 = SQ[sidx + 1], o1 = SO[sidx + 1];
  float2 kt = bf2x(kp[0]), vt = bf2x(vp[0]);
  for (int i = 0; i < LCH; i++) {
    float2 kn = {0.f, 0.f}, vn = {0.f, 0.f};
    if (i + 1 < LCH) { kn = bf2x(kp[stride * (i + 1)]); vn = bf2x(vp[stride * (i + 1)]); }
    float no = fmaxf(o0, u0 + kt.x);
    float Aa = __expf(o0 - no), Bb = __expf(u0 + kt.x - no);
    float y0 = (Aa * p0 + Bb * vt.x) / (Aa * q0 + Bb);
    no = fmaxf(o1, u1 + kt.y);
    Aa = __expf(o1 - no); Bb = __expf(u1 + kt.y - no);
    float y1 = (Aa * p1 + Bb * vt.y) / (Aa * q1 + Bb);
    if (dir == 0) {
      vp[stride * i] = f2bx(y0, y1);
    } else {
      size_t idx = base + stride * i;
      float2 rr = bf2x(rh[idx]);
      abf[idx] = f2bx(rr.x * y0, rr.y * y1);
    }
    float no2 = fmaxf(w0 + o0, kt.x);
    float A2 = __expf(w0 + o0 - no2), B2 = __expf(kt.x - no2);
    p0 = A2 * p0 + B2 * vt.x; q0 = A2 * q0 + B2; o0 = no2;
    no2 = fmaxf(w1 + o1, kt.y);
    A2 = __expf(w1 + o1 - no2); B2 = __expf(kt.y - no2);
    p1 = A2 * p1 + B2 * vt.y; q1 = A2 * q1 + B2; o1 = no2;
    kt = kn; vt = vn;
  }
}

// ---------------- final: tok2 = tok1(bf16) + gamma2*(rr*kv), transpose to NCHW fp32 -------
__global__ void k_final(const u16* __restrict__ tok1, const u16* __restrict__ rr,
                        const u16* __restrict__ kv, const float* __restrict__ gamma2,
                        float* __restrict__ out) {
  __shared__ float tile[32][33];
  int b = blockIdx.z, t0 = blockIdx.x * 32, c0 = blockIdx.y * 32;
  int cc = threadIdx.x % 32, tt0 = threadIdx.x / 32;
  size_t base = ((size_t)b * Tn + t0) * Cn + c0;
  float gam = gamma2[c0 + cc];
  for (int i = 0; i < 32; i += 8) {
    size_t idx = base + (size_t)(tt0 + i) * Cn + cc;
    tile[tt0 + i][cc] = bf2f(tok1[idx]) + gam * (bf2f(rr[idx]) * bf2f(kv[idx]));
  }
  __syncthreads();
  int tw = threadIdx.x % 32, cwi = threadIdx.x / 32;
  float* op = out + ((size_t)b * Cn + c0) * Tn + t0;
  for (int i = 0; i < 32; i += 8)
    __builtin_nontemporal_store(tile[tw][cwi + i], &op[(size_t)(cwi + i) * Tn + tw]);
}

extern "C" void kernel_launch(void* const* d_in, const int* in_sizes, int n_in, void* d_out,
                              int out_size, void* d_ws, size_t ws_size, hipStream_t stream) {
  const float* x = (const float*)d_in[0];
  const float* ln1_g = (const float*)d_in[1];
  const float* ln1_b = (const float*)d_in[2];
  const float* ln2_g = (const float*)d_in[3];
  const float* ln2_b = (const float*)d_in[4];
  const float* gamma1 = (const float*)d_in[5];
  const float* gamma2 = (const float*)d_in[6];
  const float* att_alpha = (const float*)d_in[7];
  const float* att_w1 = (const float*)d_in[8];
  const float* att_w3 = (const float*)d_in[9];
  const float* att_w5 = (const float*)d_in[10];
  const float* att_wk = (const float*)d_in[11];
  const float* att_wv = (const float*)d_in[12];
  const float* att_wr = (const float*)d_in[13];
  const float* att_wo = (const float*)d_in[14];
  const float* sp_decay = (const float*)d_in[15];
  const float* sp_first = (const float*)d_in[16];
  const float* ffn_alpha = (const float*)d_in[17];
  const float* ffn_w1 = (const float*)d_in[18];
  const float* ffn_w3 = (const float*)d_in[19];
  const float* ffn_w5 = (const float*)d_in[20];
  const float* ffn_wk = (const float*)d_in[21];
  const float* ffn_wv = (const float*)d_in[22];
  const float* ffn_wr = (const float*)d_in[23];
  float* out = (float*)d_out;

  char* ws = (char*)d_ws;
  u16* TOK = (u16*)(ws);
  u16* XS = (u16*)(ws + 24 * MB);
  u16* RRH = (u16*)(ws + 24 * MB);
  u16* ABF = (u16*)(ws + 48 * MB);
  u16* KVO = (u16*)(ws + 48 * MB);
  u16* KBH = (u16*)(ws + 72 * MB);
  u16* KKB = (u16*)(ws + 72 * MB);
  u16* VBH = (u16*)(ws + 96 * MB);
  u16* RBH = (u16*)(ws + 120 * MB);
  char* W0 = ws + 192 * MB;
  const size_t CCB = 294912;       // Cn*Cn*2 bytes
  const size_t CHB = 1179648;      // Cn*HIDn*2 bytes
  u16* wkb = (u16*)(W0);                      // QKV fused: wk|wv|wr contiguous (N=1152)
  u16* wvb = (u16*)(W0 + CCB);
  u16* wrb = (u16*)(W0 + 2 * CCB);
  u16* wob = (u16*)(W0 + 3 * CCB);
  u16* fwkb = (u16*)(W0 + 4 * CCB);           // FFN fused: fwk|fwr contiguous (N=1920)
  u16* fwrb = (u16*)(W0 + 4 * CCB + CHB);
  u16* fwvb = (u16*)(W0 + 4 * CCB + CHB + CCB);
  float* WEFF = (float*)(W0 + 4 * CCB + 2 * CHB + 2 * CCB);
  float* SUMW = WEFF + 2 * Cn * 25;
  float* SP = (float*)((char*)(SUMW + 2 * Cn) + 256);
  float* SQ = SP + NLANE;
  float* SO = SQ + NLANE;

  const int CC = Cn * Cn;            // 147456
  const int CHn = Cn * HIDn;         // 589824
  int prepN = 5 * CC + 2 * CHn + 2 * Cn * 25 + 2 * Cn;
  k_prep<<<(prepN + 255) / 256, 256, 0, stream>>>(
      att_wk, att_wv, att_wr, att_wo, ffn_wk, ffn_wr, ffn_wv,
      att_alpha, att_w1, att_w3, att_w5, ffn_alpha, ffn_w1, ffn_w3, ffn_w5,
      wkb, wvb, wrb, wob, fwkb, fwrb, fwvb, WEFF, SUMW);
  k_transpose_in<<<dim3(Tn / 32, Cn / 32, Bn), 256, 0, stream>>>(x, TOK);

  // ---- attention half ----
  k_lnnorm<<<Mn / 4, 256, 0, stream>>>(TOK, XS);
  dim3 gconv(Hn, Bn);
  k_conv<<<gconv, Cn, 0, stream>>>(XS, ln1_g, ln1_b, WEFF, SUMW, ABF);
  k_gemm<5><<<dim3(Mn / 256, 9), 512, 0, stream>>>(ABF, wkb, KBH, VBH, RBH, nullptr, nullptr,
                                                   Cn, Cn);

  // ---- chunked WKV scans (row then col; col fused with r-multiply into ABF) ----
  int gsc2 = Bn * NCH * 192 / 256;  // 384 blocks
  k_scanA<<<gsc2, 256, 0, stream>>>((u32*)KBH, (u32*)VBH, sp_decay, 0, SP, SQ, SO);
  k_scanB<<<Bn * Cn / 256, 256, 0, stream>>>(sp_decay, 0, SP, SQ, SO);
  k_scanC<<<gsc2, 256, 0, stream>>>((u32*)KBH, (u32*)VBH, nullptr, nullptr, sp_decay, sp_first,
                                    0, SP, SQ, SO);
  k_scanA<<<gsc2, 256, 0, stream>>>((u32*)KBH, (u32*)VBH, sp_decay, 1, SP, SQ, SO);
  k_scanB<<<Bn * Cn / 256, 256, 0, stream>>>(sp_decay, 1, SP, SQ, SO);
  k_scanC<<<gsc2, 256, 0, stream>>>((u32*)KBH, (u32*)VBH, (u32*)RBH, (u32*)ABF, sp_decay,
                                    sp_first, 1, SP, SQ, SO);

  k_gemm<3><<<dim3(Mn / 256, 3), 512, 0, stream>>>(ABF, wob, nullptr, nullptr, nullptr, TOK,
                                                   gamma1, Cn, Cn);

  // ---- FFN half ----
  k_lnnorm<<<Mn / 4, 256, 0, stream>>>(TOK, XS);
  k_conv<<<gconv, Cn, 0, stream>>>(XS, ln2_g, ln2_b, WEFF + 25 * Cn, SUMW + Cn, ABF);
  k_gemm<6><<<dim3(Mn / 256, 15), 512, 0, stream>>>(ABF, fwkb, KKB, RRH, nullptr, nullptr,
                                                    nullptr, Cn, Cn);
  k_gemm<4><<<dim3(Mn / 256, 3), 512, 0, stream>>>(KKB, fwvb, KVO, nullptr, nullptr, nullptr,
                                                   nullptr, HIDn, Cn);
  k_final<<<dim3(Tn / 32, Cn / 32, Bn), 256, 0, stream>>>(TOK, RRH, KVO, gamma2, out);
}

// Round 17
// 469.949 us; speedup vs baseline: 1.2202x; 1.2202x over previous
//
#include <hip/hip_runtime.h>

typedef unsigned short u16;
typedef unsigned int u32;
typedef __attribute__((ext_vector_type(8))) short short8;
typedef __attribute__((ext_vector_type(4))) float f32x4;

constexpr int Bn = 8, Cn = 384, Hn = 64, Wn = 64, Tn = Hn * Wn, Mn = Bn * Tn, HIDn = 1536;
constexpr size_t MB = 1024 * 1024;
constexpr int NCH = 64, LCH = Tn / NCH;      // 64 chunks x 64 steps
constexpr int NLANE = Bn * NCH * Cn;         // state lanes (per channel)
constexpr int CV = 8;                        // conv outputs per chunk (along w)

__device__ __forceinline__ u16 f2bf(float f) {
  unsigned u = __builtin_bit_cast(unsigned, f);
  unsigned r = (u + 0x7fffu + ((u >> 16) & 1u)) >> 16;
  return (u16)r;
}

__device__ __forceinline__ float bf2f(u16 h) {
  return __builtin_bit_cast(float, (unsigned)h << 16);
}

__device__ __forceinline__ float2 bf2x(u32 w) {
  float2 r;
  r.x = bf2f((u16)(w & 0xffffu));
  r.y = bf2f((u16)(w >> 16));
  return r;
}

__device__ __forceinline__ u32 f2bx(float a, float b) {
  return (u32)f2bf(a) | ((u32)f2bf(b) << 16);
}

__device__ __forceinline__ void gload16(const u16* g, u16* l) {
  __builtin_amdgcn_global_load_lds(
      (const __attribute__((address_space(1))) unsigned int*)(g),
      (__attribute__((address_space(3))) unsigned int*)(l), 16, 0, 0);
}

// ---------------- transpose x [B,C,T] fp32 -> tok [B,T,C] bf16 ----------------
__global__ void k_transpose_in(const float* __restrict__ x, u16* __restrict__ tok) {
  __shared__ float tile[32][33];
  int b = blockIdx.z, t0 = blockIdx.x * 32, c0 = blockIdx.y * 32;
  int tt = threadIdx.x % 32, cc = threadIdx.x / 32;
  const float* xp = x + ((size_t)b * Cn + c0) * Tn + t0;
  for (int i = 0; i < 32; i += 8) tile[cc + i][tt] = xp[(size_t)(cc + i) * Tn + tt];
  __syncthreads();
  int cw = threadIdx.x % 32, tw = threadIdx.x / 32;
  u16* op = tok + ((size_t)b * Tn + t0) * Cn + c0;
  for (int i = 0; i < 32; i += 8) op[(size_t)(tw + i) * Cn + cw] = f2bf(tile[cw][tw + i]);
}

// ---------------- one-shot weight prep: bf16 converts + effective 5x5 + sumw -------------
__global__ void k_prep(const float* __restrict__ wk, const float* __restrict__ wv,
                       const float* __restrict__ wr, const float* __restrict__ wo,
                       const float* __restrict__ fwk, const float* __restrict__ fwr,
                       const float* __restrict__ fwv,
                       const float* __restrict__ aA, const float* __restrict__ w1A,
                       const float* __restrict__ w3A, const float* __restrict__ w5A,
                       const float* __restrict__ aF, const float* __restrict__ w1F,
                       const float* __restrict__ w3F, const float* __restrict__ w5F,
                       u16* __restrict__ wkb, u16* __restrict__ wvb, u16* __restrict__ wrb,
                       u16* __restrict__ wob, u16* __restrict__ fwkb, u16* __restrict__ fwrb,
                       u16* __restrict__ fwvb, float* __restrict__ weff,
                       float* __restrict__ sumw) {
  const int CC = Cn * Cn, CH = Cn * HIDn;
  int i = blockIdx.x * 256 + threadIdx.x;
  if (i < 4 * CC) {
    int seg = i / CC, j = i % CC;
    if (seg == 0) wkb[j] = f2bf(wk[j]);
    else if (seg == 1) wvb[j] = f2bf(wv[j]);
    else if (seg == 2) wrb[j] = f2bf(wr[j]);
    else wob[j] = f2bf(wo[j]);
    return;
  }
  i -= 4 * CC;
  if (i < CH) { fwkb[i] = f2bf(fwk[i]); return; }
  i -= CH;
  if (i < CC) { fwrb[i] = f2bf(fwr[i]); return; }
  i -= CC;
  if (i < CH) { fwvb[i] = f2bf(fwv[i]); return; }
  i -= CH;
  if (i < 2 * Cn * 25) {
    int set = i / (Cn * 25), rem = i % (Cn * 25), c = rem / 25, ij = rem % 25;
    int ki = ij / 5, kj = ij % 5;
    const float* a = set ? aF : aA;
    const float* w1 = set ? w1F : w1A;
    const float* w3 = set ? w3F : w3A;
    const float* w5 = set ? w5F : w5A;
    float v = a[3] * w5[c * 25 + ij];
    if (ki >= 1 && ki <= 3 && kj >= 1 && kj <= 3) v += a[2] * w3[c * 9 + (ki - 1) * 3 + (kj - 1)];
    if (ki == 2 && kj == 2) v += a[1] * w1[c] + a[0];
    weff[(set * 25 + ij) * Cn + c] = v;
    return;
  }
  i -= 2 * Cn * 25;
  if (i < 2 * Cn) {
    int set = i / Cn, c = i % Cn;
    const float* a = set ? aF : aA;
    const float* w1 = set ? w1F : w1A;
    const float* w3 = set ? w3F : w3A;
    const float* w5 = set ? w5F : w5A;
    float s = 0.f;
    for (int ij = 0; ij < 25; ij++) {
      int ki = ij / 5, kj = ij % 5;
      float v = a[3] * w5[c * 25 + ij];
      if (ki >= 1 && ki <= 3 && kj >= 1 && kj <= 3)
        v += a[2] * w3[c * 9 + (ki - 1) * 3 + (kj - 1)];
      if (ki == 2 && kj == 2) v += a[1] * w1[c] + a[0];
      s += v;
    }
    sumw[i] = s;
  }
}

// ---------------- fused LN: stats + write normalized x as bf16 (bf16 in) ----------------
__global__ void k_lnnorm(const u16* __restrict__ tok, u16* __restrict__ xs) {
  int token = blockIdx.x * 4 + (threadIdx.x >> 6);
  int lane = threadIdx.x & 63;
  const u32* p = (const u32*)(tok + (size_t)token * Cn);
  float v[6];
  float s = 0.f, s2 = 0.f;
#pragma unroll
  for (int j = 0; j < 3; j++) {
    float2 f = bf2x(p[lane + j * 64]);
    v[2 * j] = f.x; v[2 * j + 1] = f.y;
    s += f.x + f.y;
    s2 += f.x * f.x + f.y * f.y;
  }
  for (int off = 32; off; off >>= 1) { s += __shfl_xor(s, off); s2 += __shfl_xor(s2, off); }
  float m = s * (1.0f / Cn);
  float r = rsqrtf(s2 * (1.0f / Cn) - m * m + 1e-5f);
  u32* op = (u32*)(xs + (size_t)token * Cn);
#pragma unroll
  for (int j = 0; j < 3; j++)
    op[lane + j * 64] = f2bx((v[2 * j] - m) * r, (v[2 * j + 1] - m) * r);
}

// ---------------- 5x5 depthwise conv on normalized x (bf16 in/out) ----------------
__global__ __launch_bounds__(384) void k_conv(const u16* __restrict__ xs,
                                              const float* __restrict__ g,
                                              const float* __restrict__ bb,
                                              const float* __restrict__ weff,
                                              const float* __restrict__ sumw,
                                              u16* __restrict__ out) {
  int c = threadIdx.x;
  int h = blockIdx.x, b = blockIdx.y;
  float gc = g[c], bc = bb[c], s0 = sumw[c];
  float wv[25];
#pragma unroll
  for (int i = 0; i < 25; i++) wv[i] = weff[i * Cn + c];
  const u16* base = xs + (size_t)b * Tn * Cn + c;
  u16* orow = out + ((size_t)b * Tn + (size_t)h * Wn) * Cn + c;
  bool hOK = (h >= 2 && h <= Hn - 3);
  for (int w0 = 0; w0 < Wn; w0 += CV) {
    float acc[CV];
#pragma unroll
    for (int v = 0; v < CV; v++) acc[v] = 0.f;
    if (hOK && w0 != 0 && w0 != Wn - CV) {
#pragma unroll
      for (int ki = 0; ki < 5; ki++) {
        int rowt = (h + ki - 2) * Wn + w0 - 2;
#pragma unroll
        for (int jj = 0; jj < CV + 4; jj++) {
          float y = bf2f(base[(size_t)(rowt + jj) * Cn]);
#pragma unroll
          for (int v = 0; v < CV; v++) {
            int kj = jj - v;
            if (kj >= 0 && kj < 5) acc[v] = fmaf(y, wv[ki * 5 + kj], acc[v]);
          }
        }
      }
      u16* op = orow + (size_t)w0 * Cn;
#pragma unroll
      for (int v = 0; v < CV; v++) op[(size_t)v * Cn] = f2bf(gc * acc[v] + bc * s0);
    } else {
      float sw[CV];
#pragma unroll
      for (int v = 0; v < CV; v++) sw[v] = 0.f;
#pragma unroll
      for (int ki = 0; ki < 5; ki++) {
        int hh = h + ki - 2;
        if ((unsigned)hh >= (unsigned)Hn) continue;
#pragma unroll
        for (int jj = 0; jj < CV + 4; jj++) {
          int ww = w0 + jj - 2;
          if ((unsigned)ww >= (unsigned)Wn) continue;
          float y = bf2f(base[(size_t)(hh * Wn + ww) * Cn]);
#pragma unroll
          for (int v = 0; v < CV; v++) {
            int kj = jj - v;
            if (kj >= 0 && kj < 5) {
              float wt = wv[ki * 5 + kj];
              acc[v] = fmaf(y, wt, acc[v]);
              sw[v] += wt;
            }
          }
        }
      }
      u16* op = orow + (size_t)w0 * Cn;
#pragma unroll
      for (int v = 0; v < CV; v++) op[(size_t)v * Cn] = f2bf(gc * acc[v] + bc * sw[v]);
    }
  }
}

// ---- bf16 GEMM: 256x128 tile, 512 thr, BK=32, XOR swizzle, XCD remap ----
// 3-buffer pipeline with COUNTED vmcnt (loads stay in flight across barriers).
// MODE 3: tokH += gamma*val (bf16 in place, stride N)
// MODE 4: plain bf16 -> o1 (stride N)
// MODE 5: fused QKV: seg0->o1, seg1->o2, seg2->sigmoid->o3 (each stride 384)
// MODE 6: fused FFN: seg0->relu^2->o1 (stride 1536), seg1->sigmoid->o2 (stride 384)
template <int MODE>
__global__ __launch_bounds__(512) void k_gemm(const u16* __restrict__ A,
                                              const u16* __restrict__ Wt,
                                              u16* __restrict__ o1, u16* __restrict__ o2,
                                              u16* __restrict__ o3,
                                              u16* __restrict__ tokH,
                                              const float* __restrict__ gamma, int K, int N) {
  __shared__ u16 lds_a[3][256 * 32];
  __shared__ u16 lds_b[3][128 * 32];
  int tid = threadIdx.x;
  int id = blockIdx.y * gridDim.x + blockIdx.x;
  int xcd = id & 7, q = id >> 3;
  int gx8 = gridDim.x >> 3;                  // gridDim.x == 128 -> 16
  int bm = ((q % gx8) * 8 + xcd) * 256;
  int bn = (q / gx8) * 128;
  int wave = tid >> 6, lane = tid & 63;
  int wm = (wave >> 1) * 64, wn = (wave & 1) * 64;
  int lr = lane & 15, kg = lane >> 4;

  f32x4 acc[4][4];
#pragma unroll
  for (int i = 0; i < 4; i++)
#pragma unroll
    for (int j = 0; j < 4; j++) acc[i][j] = f32x4{0.f, 0.f, 0.f, 0.f};

  int r0 = tid >> 2;           // 0..127
  int fslot = tid & 3;
  int row2 = r0 + 128;
  int kgrA0 = fslot ^ ((r0 >> 1) & 3);
  int kgrA1 = fslot ^ ((row2 >> 1) & 3);
  const u16* gA0 = A + (size_t)(bm + r0) * K + kgrA0 * 8;
  const u16* gA1 = A + (size_t)(bm + row2) * K + kgrA1 * 8;
  const u16* gB0 = Wt + (size_t)(bn + r0) * K + kgrA0 * 8;
  int nk = K >> 5;

  gload16(gA0, &lds_a[0][tid * 8]);
  gload16(gA1, &lds_a[0][(tid + 512) * 8]);
  gload16(gB0, &lds_b[0][tid * 8]);
  gload16(gA0 + 32, &lds_a[1][tid * 8]);
  gload16(gA1 + 32, &lds_a[1][(tid + 512) * 8]);
  gload16(gB0 + 32, &lds_b[1][tid * 8]);

  for (int t = 0; t < nk; ++t) {
    int cur = t % 3;
    if (t + 2 < nk) {
      int k0 = (t + 2) << 5;
      int nb = (t + 2) % 3;
      gload16(gA0 + k0, &lds_a[nb][tid * 8]);
      gload16(gA1 + k0, &lds_a[nb][(tid + 512) * 8]);
      gload16(gB0 + k0, &lds_b[nb][tid * 8]);
      asm volatile("s_waitcnt vmcnt(6)" ::: "memory");
    } else if (t + 1 < nk) {
      asm volatile("s_waitcnt vmcnt(3)" ::: "memory");
    } else {
      asm volatile("s_waitcnt vmcnt(0)" ::: "memory");
    }
    __builtin_amdgcn_s_barrier();
    const u16* la = lds_a[cur];
    const u16* lb = lds_b[cur];
    short8 af[4], bfr[4];
#pragma unroll
    for (int mi = 0; mi < 4; mi++) {
      int row = wm + mi * 16 + lr;
      af[mi] = *(const short8*)&la[row * 32 + (kg ^ ((row >> 1) & 3)) * 8];
    }
#pragma unroll
    for (int ni = 0; ni < 4; ni++) {
      int row = wn + ni * 16 + lr;
      bfr[ni] = *(const short8*)&lb[row * 32 + (kg ^ ((row >> 1) & 3)) * 8];
    }
#pragma unroll
    for (int mi = 0; mi < 4; mi++)
#pragma unroll
      for (int ni = 0; ni < 4; ni++)
        acc[mi][ni] = __builtin_amdgcn_mfma_f32_16x16x32_bf16(af[mi], bfr[ni], acc[mi][ni], 0, 0, 0);
    __builtin_amdgcn_s_barrier();
  }

  int seg = 0;
  if (MODE == 5) seg = bn / 384;
  if (MODE == 6) seg = (bn >= 1536) ? 1 : 0;

#pragma unroll
  for (int mi = 0; mi < 4; mi++)
#pragma unroll
    for (int ni = 0; ni < 4; ni++) {
#pragma unroll
      for (int r = 0; r < 4; r++) {
        int gr = bm + wm + mi * 16 + kg * 4 + r;
        int gc = bn + wn + ni * 16 + lr;
        float v = acc[mi][ni][r];
        if (MODE == 3) {
          size_t idx = (size_t)gr * N + gc;
          tokH[idx] = f2bf(bf2f(tokH[idx]) + gamma[gc] * v);
        } else if (MODE == 4) {
          o1[(size_t)gr * N + gc] = f2bf(v);
        } else if (MODE == 5) {
          int col = gc - seg * 384;
          size_t idx = (size_t)gr * 384 + col;
          if (seg == 0) o1[idx] = f2bf(v);
          else if (seg == 1) o2[idx] = f2bf(v);
          else o3[idx] = f2bf(1.0f / (1.0f + __expf(-v)));
        } else if (MODE == 6) {
          if (seg == 0) {
            float tpos = fmaxf(v, 0.0f);
            o1[(size_t)gr * 1536 + gc] = f2bf(tpos * tpos);
          } else {
            o2[(size_t)gr * 384 + (gc - 1536)] = f2bf(1.0f / (1.0f + __expf(-v)));
          }
        }
      }
    }
}

// ---------------- chunked WKV scan (bf16 k/v packed u32, 2 channels/thread) ----------------
__global__ void k_scanA(const u32* __restrict__ k, const u32* __restrict__ v,
                        const float* __restrict__ decay, int dir,
                        float* __restrict__ SP, float* __restrict__ SQ, float* __restrict__ SO) {
  int gid = blockIdx.x * 256 + threadIdx.x;   // over Bn*NCH*192
  int cp = gid % 192;
  int ch = (gid / 192) % NCH;
  int b = gid / (192 * NCH);
  int c = cp * 2;
  float w0 = decay[dir * Cn + c] * (1.0f / Tn);
  float w1 = decay[dir * Cn + c + 1] * (1.0f / Tn);
  size_t be = dir ? ((size_t)b * Tn + ch) * Cn + c : ((size_t)b * Tn + (size_t)ch * LCH) * Cn + c;
  size_t base = be >> 1;
  size_t stride = (dir ? (size_t)Wn * Cn : (size_t)Cn) >> 1;
  const u32* kp = k + base;
  const u32* vp = v + base;
  float p0 = 0.f, q0 = 0.f, o0 = -1e30f, p1 = 0.f, q1 = 0.f, o1 = -1e30f;
  float2 kt = bf2x(kp[0]), vt = bf2x(vp[0]);
  for (int i = 0; i < LCH; i++) {
    float2 kn = {0.f, 0.f}, vn = {0.f, 0.f};
    if (i + 1 < LCH) { kn = bf2x(kp[stride * (i + 1)]); vn = bf2x(vp[stride * (i + 1)]); }
    float no = fmaxf(w0 + o0, kt.x);
    float Aa = __expf(w0 + o0 - no), Bb = __expf(kt.x - no);
    p0 = Aa * p0 + Bb * vt.x; q0 = Aa * q0 + Bb; o0 = no;
    no = fmaxf(w1 + o1, kt.y);
    Aa = __expf(w1 + o1 - no); Bb = __expf(kt.y - no);
    p1 = Aa * p1 + Bb * vt.y; q1 = Aa * q1 + Bb; o1 = no;
    kt = kn; vt = vn;
  }
  size_t sidx = ((size_t)b * NCH + ch) * Cn + c;
  SP[sidx] = p0; SP[sidx + 1] = p1;
  SQ[sidx] = q0; SQ[sidx + 1] = q1;
  SO[sidx] = o0; SO[sidx + 1] = o1;
}

__global__ void k_scanB(const float* __restrict__ decay, int dir,
                        float* __restrict__ SP, float* __restrict__ SQ, float* __restrict__ SO) {
  int gid = blockIdx.x * 256 + threadIdx.x;  // B*C
  int c = gid % Cn, b = gid / Cn;
  float wL = decay[dir * Cn + c] * (1.0f / Tn) * LCH;
  float p = 0.f, q = 0.f, o = -1e30f;
  size_t idx = (size_t)b * NCH * Cn + c;
  float lp = SP[idx], lq = SQ[idx], lo = SO[idx];
  for (int ch = 0; ch < NCH; ch++) {
    float np_ = 0.f, nq_ = 0.f, no_ = 0.f;
    if (ch + 1 < NCH) { np_ = SP[idx + Cn]; nq_ = SQ[idx + Cn]; no_ = SO[idx + Cn]; }
    SP[idx] = p; SQ[idx] = q; SO[idx] = o;
    float o1 = o + wL;
    float no = fmaxf(o1, lo);
    float e1 = __expf(o1 - no), e2 = __expf(lo - no);
    p = p * e1 + lp * e2;
    q = q * e1 + lq * e2;
    o = no;
    lp = np_; lq = nq_; lo = no_;
    idx += Cn;
  }
}

// Phase C: replay chunk. dir0: y -> v (in place). dir1: abf = bf16(r*y) (fused).
__global__ void k_scanC(const u32* __restrict__ k, u32* __restrict__ v,
                        const u32* __restrict__ rh, u32* __restrict__ abf,
                        const float* __restrict__ decay, const float* __restrict__ first, int dir,
                        const float* __restrict__ SP, const float* __restrict__ SQ,
                        const float* __restrict__ SO) {
  int gid = blockIdx.x * 256 + threadIdx.x;
  int cp = gid % 192;
  int ch = (gid / 192) % NCH;
  int b = gid / (192 * NCH);
  int c = cp * 2;
  float w0 = decay[dir * Cn + c] * (1.0f / Tn);
  float w1 = decay[dir * Cn + c + 1] * (1.0f / Tn);
  float u0 = first[dir * Cn + c] * (1.0f / Tn);
  float u1 = first[dir * Cn + c + 1] * (1.0f / Tn);
  size_t be = dir ? ((size_t)b * Tn + ch) * Cn + c : ((size_t)b * Tn + (size_t)ch * LCH) * Cn + c;
  size_t base = be >> 1;
  size_t stride = (dir ? (size_t)Wn * Cn : (size_t)Cn) >> 1;
  const u32* kp = k + base;
  u32* vp = v + base;
  size_t sidx = ((size_t)b * NCH + ch) * Cn + c;
  float p0 = SP[sidx], q0 = SQ[sidx], o0 = SO[sidx];
  float p1 = SP[sidx + 1], q1 = SQ[sidx + 1], o1 = SO[sidx + 1];
  float2 kt = bf2x(kp[0]), vt = bf2x(vp[0]);
  for (int i = 0; i < LCH; i++) {
    float2 kn = {0.f, 0.f}, vn = {0.f, 0.f};
    if (i + 1 < LCH) { kn = bf2x(kp[stride * (i + 1)]); vn = bf2x(vp[stride * (i + 1)]); }
    float no = fmaxf(o0, u0 + kt.x);
    float Aa = __expf(o0 - no), Bb = __expf(u0 + kt.x - no);
    float y0 = (Aa * p0 + Bb * vt.x) / (Aa * q0 + Bb);
    no = fmaxf(o1, u1 + kt.y);
    Aa = __expf(o1 - no); Bb = __expf(u1 + kt.y - no);
    float y1 = (Aa * p1 + Bb * vt.y) / (Aa * q1 + Bb);
    if (dir == 0) {
      vp[stride * i] = f2bx(y0, y1);
    } else {
      size_t idx = base + stride * i;
      float2 rr = bf2x(rh[idx]);
      abf[idx] = f2bx(rr.x * y0, rr.y * y1);
    }
    float no2 = fmaxf(w0 + o0, kt.x);
    float A2 = __expf(w0 + o0 - no2), B2 = __expf(kt.x - no2);
    p0 = A2 * p0 + B2 * vt.x; q0 = A2 * q0 + B2; o0 = no2;
    no2 = fmaxf(w1 + o1, kt.y);
    A2 = __expf(w1 + o1 - no2); B2 = __expf(kt.y - no2);
    p1 = A2 * p1 + B2 * vt.y; q1 = A2 * q1 + B2; o1 = no2;
    kt = kn; vt = vn;
  }
}

// ---------------- final: tok2 = tok1(bf16) + gamma2*(rr*kv), transpose to NCHW fp32 -------
__global__ void k_final(const u16* __restrict__ tok1, const u16* __restrict__ rr,
                        const u16* __restrict__ kv, const float* __restrict__ gamma2,
                        float* __restrict__ out) {
  __shared__ float tile[32][33];
  int b = blockIdx.z, t0 = blockIdx.x * 32, c0 = blockIdx.y * 32;
  int cc = threadIdx.x % 32, tt0 = threadIdx.x / 32;
  size_t base = ((size_t)b * Tn + t0) * Cn + c0;
  float gam = gamma2[c0 + cc];
  for (int i = 0; i < 32; i += 8) {
    size_t idx = base + (size_t)(tt0 + i) * Cn + cc;
    tile[tt0 + i][cc] = bf2f(tok1[idx]) + gam * (bf2f(rr[idx]) * bf2f(kv[idx]));
  }
  __syncthreads();
  int tw = threadIdx.x % 32, cwi = threadIdx.x / 32;
  float* op = out + ((size_t)b * Cn + c0) * Tn + t0;
  for (int i = 0; i < 32; i += 8) op[(size_t)(cwi + i) * Tn + tw] = tile[tw][cwi + i];
}

extern "C" void kernel_launch(void* const* d_in, const int* in_sizes, int n_in, void* d_out,
                              int out_size, void* d_ws, size_t ws_size, hipStream_t stream) {
  const float* x = (const float*)d_in[0];
  const float* ln1_g = (const float*)d_in[1];
  const float* ln1_b = (const float*)d_in[2];
  const float* ln2_g = (const float*)d_in[3];
  const float* ln2_b = (const float*)d_in[4];
  const float* gamma1 = (const float*)d_in[5];
  const float* gamma2 = (const float*)d_in[6];
  const float* att_alpha = (const float*)d_in[7];
  const float* att_w1 = (const float*)d_in[8];
  const float* att_w3 = (const float*)d_in[9];
  const float* att_w5 = (const float*)d_in[10];
  const float* att_wk = (const float*)d_in[11];
  const float* att_wv = (const float*)d_in[12];
  const float* att_wr = (const float*)d_in[13];
  const float* att_wo = (const float*)d_in[14];
  const float* sp_decay = (const float*)d_in[15];
  const float* sp_first = (const float*)d_in[16];
  const float* ffn_alpha = (const float*)d_in[17];
  const float* ffn_w1 = (const float*)d_in[18];
  const float* ffn_w3 = (const float*)d_in[19];
  const float* ffn_w5 = (const float*)d_in[20];
  const float* ffn_wk = (const float*)d_in[21];
  const float* ffn_wv = (const float*)d_in[22];
  const float* ffn_wr = (const float*)d_in[23];
  float* out = (float*)d_out;

  char* ws = (char*)d_ws;
  u16* TOK = (u16*)(ws);
  u16* XS = (u16*)(ws + 24 * MB);
  u16* RRH = (u16*)(ws + 24 * MB);
  u16* ABF = (u16*)(ws + 48 * MB);
  u16* KVO = (u16*)(ws + 48 * MB);
  u16* KBH = (u16*)(ws + 72 * MB);
  u16* KKB = (u16*)(ws + 72 * MB);
  u16* VBH = (u16*)(ws + 96 * MB);
  u16* RBH = (u16*)(ws + 120 * MB);
  char* W0 = ws + 192 * MB;
  const size_t CCB = 294912;       // Cn*Cn*2 bytes
  const size_t CHB = 1179648;      // Cn*HIDn*2 bytes
  u16* wkb = (u16*)(W0);                      // QKV fused: wk|wv|wr contiguous (N=1152)
  u16* wvb = (u16*)(W0 + CCB);
  u16* wrb = (u16*)(W0 + 2 * CCB);
  u16* wob = (u16*)(W0 + 3 * CCB);
  u16* fwkb = (u16*)(W0 + 4 * CCB);           // FFN fused: fwk|fwr contiguous (N=1920)
  u16* fwrb = (u16*)(W0 + 4 * CCB + CHB);
  u16* fwvb = (u16*)(W0 + 4 * CCB + CHB + CCB);
  float* WEFF = (float*)(W0 + 4 * CCB + 2 * CHB + 2 * CCB);
  float* SUMW = WEFF + 2 * Cn * 25;
  float* SP = (float*)((char*)(SUMW + 2 * Cn) + 256);
  float* SQ = SP + NLANE;
  float* SO = SQ + NLANE;

  const int CC = Cn * Cn;            // 147456
  const int CHn = Cn * HIDn;         // 589824
  int prepN = 5 * CC + 2 * CHn + 2 * Cn * 25 + 2 * Cn;
  k_prep<<<(prepN + 255) / 256, 256, 0, stream>>>(
      att_wk, att_wv, att_wr, att_wo, ffn_wk, ffn_wr, ffn_wv,
      att_alpha, att_w1, att_w3, att_w5, ffn_alpha, ffn_w1, ffn_w3, ffn_w5,
      wkb, wvb, wrb, wob, fwkb, fwrb, fwvb, WEFF, SUMW);
  k_transpose_in<<<dim3(Tn / 32, Cn / 32, Bn), 256, 0, stream>>>(x, TOK);

  // ---- attention half ----
  k_lnnorm<<<Mn / 4, 256, 0, stream>>>(TOK, XS);
  dim3 gconv(Hn, Bn);
  k_conv<<<gconv, Cn, 0, stream>>>(XS, ln1_g, ln1_b, WEFF, SUMW, ABF);
  k_gemm<5><<<dim3(Mn / 256, 9), 512, 0, stream>>>(ABF, wkb, KBH, VBH, RBH, nullptr, nullptr,
                                                   Cn, Cn);

  // ---- chunked WKV scans (row then col; col fused with r-multiply into ABF) ----
  int gsc2 = Bn * NCH * 192 / 256;  // 384 blocks
  k_scanA<<<gsc2, 256, 0, stream>>>((u32*)KBH, (u32*)VBH, sp_decay, 0, SP, SQ, SO);
  k_scanB<<<Bn * Cn / 256, 256, 0, stream>>>(sp_decay, 0, SP, SQ, SO);
  k_scanC<<<gsc2, 256, 0, stream>>>((u32*)KBH, (u32*)VBH, nullptr, nullptr, sp_decay, sp_first,
                                    0, SP, SQ, SO);
  k_scanA<<<gsc2, 256, 0, stream>>>((u32*)KBH, (u32*)VBH, sp_decay, 1, SP, SQ, SO);
  k_scanB<<<Bn * Cn / 256, 256, 0, stream>>>(sp_decay, 1, SP, SQ, SO);
  k_scanC<<<gsc2, 256, 0, stream>>>((u32*)KBH, (u32*)VBH, (u32*)RBH, (u32*)ABF, sp_decay,
                                    sp_first, 1, SP, SQ, SO);

  k_gemm<3><<<dim3(Mn / 256, 3), 512, 0, stream>>>(ABF, wob, nullptr, nullptr, nullptr, TOK,
                                                   gamma1, Cn, Cn);

  // ---- FFN half ----
  k_lnnorm<<<Mn / 4, 256, 0, stream>>>(TOK, XS);
  k_conv<<<gconv, Cn, 0, stream>>>(XS, ln2_g, ln2_b, WEFF + 25 * Cn, SUMW + Cn, ABF);
  k_gemm<6><<<dim3(Mn / 256, 15), 512, 0, stream>>>(ABF, fwkb, KKB, RRH, nullptr, nullptr,
                                                    nullptr, Cn, Cn);
  k_gemm<4><<<dim3(Mn / 256, 3), 512, 0, stream>>>(KKB, fwvb, KVO, nullptr, nullptr, nullptr,
                                                   nullptr, HIDn, Cn);
  k_final<<<dim3(Tn / 32, Cn / 32, Bn), 256, 0, stream>>>(TOK, RRH, KVO, gamma2, out);
}

// Round 18
// 469.898 us; speedup vs baseline: 1.2203x; 1.0001x over previous
//
#include <hip/hip_runtime.h>

typedef unsigned short u16;
typedef unsigned int u32;
typedef __attribute__((ext_vector_type(8))) short short8;
typedef __attribute__((ext_vector_type(4))) float f32x4;

constexpr int Bn = 8, Cn = 384, Hn = 64, Wn = 64, Tn = Hn * Wn, Mn = Bn * Tn, HIDn = 1536;
constexpr size_t MB = 1024 * 1024;
constexpr int NCH = 64, LCH = Tn / NCH;      // 64 chunks x 64 steps
constexpr int NLANE = Bn * NCH * Cn;         // state lanes (per channel)
constexpr int CV = 8;                        // conv outputs per chunk (along w)

__device__ __forceinline__ u16 f2bf(float f) {
  unsigned u = __builtin_bit_cast(unsigned, f);
  unsigned r = (u + 0x7fffu + ((u >> 16) & 1u)) >> 16;
  return (u16)r;
}

__device__ __forceinline__ float bf2f(u16 h) {
  return __builtin_bit_cast(float, (unsigned)h << 16);
}

__device__ __forceinline__ float2 bf2x(u32 w) {
  float2 r;
  r.x = bf2f((u16)(w & 0xffffu));
  r.y = bf2f((u16)(w >> 16));
  return r;
}

__device__ __forceinline__ u32 f2bx(float a, float b) {
  return (u32)f2bf(a) | ((u32)f2bf(b) << 16);
}

__device__ __forceinline__ void gload16(const u16* g, u16* l) {
  __builtin_amdgcn_global_load_lds(
      (const __attribute__((address_space(1))) unsigned int*)(g),
      (__attribute__((address_space(3))) unsigned int*)(l), 16, 0, 0);
}

// ---------------- transpose x [B,C,T] fp32 -> tok [B,T,C] bf16 ----------------
__global__ void k_transpose_in(const float* __restrict__ x, u16* __restrict__ tok) {
  __shared__ float tile[32][33];
  int b = blockIdx.z, t0 = blockIdx.x * 32, c0 = blockIdx.y * 32;
  int tt = threadIdx.x % 32, cc = threadIdx.x / 32;
  const float* xp = x + ((size_t)b * Cn + c0) * Tn + t0;
  for (int i = 0; i < 32; i += 8) tile[cc + i][tt] = xp[(size_t)(cc + i) * Tn + tt];
  __syncthreads();
  int cw = threadIdx.x % 32, tw = threadIdx.x / 32;
  u16* op = tok + ((size_t)b * Tn + t0) * Cn + c0;
  for (int i = 0; i < 32; i += 8) op[(size_t)(tw + i) * Cn + cw] = f2bf(tile[cw][tw + i]);
}

// ---------------- one-shot weight prep: bf16 converts + effective 5x5 + sumw -------------
__global__ void k_prep(const float* __restrict__ wk, const float* __restrict__ wv,
                       const float* __restrict__ wr, const float* __restrict__ wo,
                       const float* __restrict__ fwk, const float* __restrict__ fwr,
                       const float* __restrict__ fwv,
                       const float* __restrict__ aA, const float* __restrict__ w1A,
                       const float* __restrict__ w3A, const float* __restrict__ w5A,
                       const float* __restrict__ aF, const float* __restrict__ w1F,
                       const float* __restrict__ w3F, const float* __restrict__ w5F,
                       u16* __restrict__ wkb, u16* __restrict__ wvb, u16* __restrict__ wrb,
                       u16* __restrict__ wob, u16* __restrict__ fwkb, u16* __restrict__ fwrb,
                       u16* __restrict__ fwvb, float* __restrict__ weff,
                       float* __restrict__ sumw) {
  const int CC = Cn * Cn, CH = Cn * HIDn;
  int i = blockIdx.x * 256 + threadIdx.x;
  if (i < 4 * CC) {
    int seg = i / CC, j = i % CC;
    if (seg == 0) wkb[j] = f2bf(wk[j]);
    else if (seg == 1) wvb[j] = f2bf(wv[j]);
    else if (seg == 2) wrb[j] = f2bf(wr[j]);
    else wob[j] = f2bf(wo[j]);
    return;
  }
  i -= 4 * CC;
  if (i < CH) { fwkb[i] = f2bf(fwk[i]); return; }
  i -= CH;
  if (i < CC) { fwrb[i] = f2bf(fwr[i]); return; }
  i -= CC;
  if (i < CH) { fwvb[i] = f2bf(fwv[i]); return; }
  i -= CH;
  if (i < 2 * Cn * 25) {
    int set = i / (Cn * 25), rem = i % (Cn * 25), c = rem / 25, ij = rem % 25;
    int ki = ij / 5, kj = ij % 5;
    const float* a = set ? aF : aA;
    const float* w1 = set ? w1F : w1A;
    const float* w3 = set ? w3F : w3A;
    const float* w5 = set ? w5F : w5A;
    float v = a[3] * w5[c * 25 + ij];
    if (ki >= 1 && ki <= 3 && kj >= 1 && kj <= 3) v += a[2] * w3[c * 9 + (ki - 1) * 3 + (kj - 1)];
    if (ki == 2 && kj == 2) v += a[1] * w1[c] + a[0];
    weff[(set * 25 + ij) * Cn + c] = v;
    return;
  }
  i -= 2 * Cn * 25;
  if (i < 2 * Cn) {
    int set = i / Cn, c = i % Cn;
    const float* a = set ? aF : aA;
    const float* w1 = set ? w1F : w1A;
    const float* w3 = set ? w3F : w3A;
    const float* w5 = set ? w5F : w5A;
    float s = 0.f;
    for (int ij = 0; ij < 25; ij++) {
      int ki = ij / 5, kj = ij % 5;
      float v = a[3] * w5[c * 25 + ij];
      if (ki >= 1 && ki <= 3 && kj >= 1 && kj <= 3)
        v += a[2] * w3[c * 9 + (ki - 1) * 3 + (kj - 1)];
      if (ki == 2 && kj == 2) v += a[1] * w1[c] + a[0];
      s += v;
    }
    sumw[i] = s;
  }
}

// ---------------- fused LN: stats + write normalized x as bf16 (bf16 in) ----------------
__global__ void k_lnnorm(const u16* __restrict__ tok, u16* __restrict__ xs) {
  int token = blockIdx.x * 4 + (threadIdx.x >> 6);
  int lane = threadIdx.x & 63;
  const u32* p = (const u32*)(tok + (size_t)token * Cn);
  float v[6];
  float s = 0.f, s2 = 0.f;
#pragma unroll
  for (int j = 0; j < 3; j++) {
    float2 f = bf2x(p[lane + j * 64]);
    v[2 * j] = f.x; v[2 * j + 1] = f.y;
    s += f.x + f.y;
    s2 += f.x * f.x + f.y * f.y;
  }
  for (int off = 32; off; off >>= 1) { s += __shfl_xor(s, off); s2 += __shfl_xor(s2, off); }
  float m = s * (1.0f / Cn);
  float r = rsqrtf(s2 * (1.0f / Cn) - m * m + 1e-5f);
  u32* op = (u32*)(xs + (size_t)token * Cn);
#pragma unroll
  for (int j = 0; j < 3; j++)
    op[lane + j * 64] = f2bx((v[2 * j] - m) * r, (v[2 * j + 1] - m) * r);
}

// ---------------- 5x5 depthwise conv on normalized x (bf16 in/out) ----------------
__global__ __launch_bounds__(384) void k_conv(const u16* __restrict__ xs,
                                              const float* __restrict__ g,
                                              const float* __restrict__ bb,
                                              const float* __restrict__ weff,
                                              const float* __restrict__ sumw,
                                              u16* __restrict__ out) {
  int c = threadIdx.x;
  int h = blockIdx.x, b = blockIdx.y;
  float gc = g[c], bc = bb[c], s0 = sumw[c];
  float wv[25];
#pragma unroll
  for (int i = 0; i < 25; i++) wv[i] = weff[i * Cn + c];
  const u16* base = xs + (size_t)b * Tn * Cn + c;
  u16* orow = out + ((size_t)b * Tn + (size_t)h * Wn) * Cn + c;
  bool hOK = (h >= 2 && h <= Hn - 3);
  for (int w0 = 0; w0 < Wn; w0 += CV) {
    float acc[CV];
#pragma unroll
    for (int v = 0; v < CV; v++) acc[v] = 0.f;
    if (hOK && w0 != 0 && w0 != Wn - CV) {
#pragma unroll
      for (int ki = 0; ki < 5; ki++) {
        int rowt = (h + ki - 2) * Wn + w0 - 2;
#pragma unroll
        for (int jj = 0; jj < CV + 4; jj++) {
          float y = bf2f(base[(size_t)(rowt + jj) * Cn]);
#pragma unroll
          for (int v = 0; v < CV; v++) {
            int kj = jj - v;
            if (kj >= 0 && kj < 5) acc[v] = fmaf(y, wv[ki * 5 + kj], acc[v]);
          }
        }
      }
      u16* op = orow + (size_t)w0 * Cn;
#pragma unroll
      for (int v = 0; v < CV; v++) op[(size_t)v * Cn] = f2bf(gc * acc[v] + bc * s0);
    } else {
      float sw[CV];
#pragma unroll
      for (int v = 0; v < CV; v++) sw[v] = 0.f;
#pragma unroll
      for (int ki = 0; ki < 5; ki++) {
        int hh = h + ki - 2;
        if ((unsigned)hh >= (unsigned)Hn) continue;
#pragma unroll
        for (int jj = 0; jj < CV + 4; jj++) {
          int ww = w0 + jj - 2;
          if ((unsigned)ww >= (unsigned)Wn) continue;
          float y = bf2f(base[(size_t)(hh * Wn + ww) * Cn]);
#pragma unroll
          for (int v = 0; v < CV; v++) {
            int kj = jj - v;
            if (kj >= 0 && kj < 5) {
              float wt = wv[ki * 5 + kj];
              acc[v] = fmaf(y, wt, acc[v]);
              sw[v] += wt;
            }
          }
        }
      }
      u16* op = orow + (size_t)w0 * Cn;
#pragma unroll
      for (int v = 0; v < CV; v++) op[(size_t)v * Cn] = f2bf(gc * acc[v] + bc * sw[v]);
    }
  }
}

// ---- bf16 GEMM: 256x128 tile, 512 thr, BK=32, XOR swizzle, N-inner XCD remap ----
// Per XCD: sweep all N-blocks of one 256-row M-panel before advancing M.
// Hot set = A-panel (<=768KB) + whole B (<=1.4MB) -> L2-resident; A fetched once.
// 3-buffer pipeline with COUNTED vmcnt (loads stay in flight across barriers).
// MODE 3: tokH += gamma*val (bf16 in place, stride N)
// MODE 4: plain bf16 -> o1 (stride N)
// MODE 5: fused QKV: seg0->o1, seg1->o2, seg2->sigmoid->o3 (each stride 384)
// MODE 6: fused FFN: seg0->relu^2->o1 (stride 1536), seg1->sigmoid->o2 (stride 384)
template <int MODE>
__global__ __launch_bounds__(512) void k_gemm(const u16* __restrict__ A,
                                              const u16* __restrict__ Wt,
                                              u16* __restrict__ o1, u16* __restrict__ o2,
                                              u16* __restrict__ o3,
                                              u16* __restrict__ tokH,
                                              const float* __restrict__ gamma, int K, int N) {
  __shared__ u16 lds_a[3][256 * 32];
  __shared__ u16 lds_b[3][128 * 32];
  int tid = threadIdx.x;
  int id = blockIdx.y * gridDim.x + blockIdx.x;
  int xcd = id & 7, q = id >> 3;
  int nN = gridDim.y;                        // N-blocks
  int bn = (q % nN) * 128;
  int bm = ((q / nN) * 8 + xcd) * 256;       // N-inner: all N for one M-panel per XCD
  int wave = tid >> 6, lane = tid & 63;
  int wm = (wave >> 1) * 64, wn = (wave & 1) * 64;
  int lr = lane & 15, kg = lane >> 4;

  f32x4 acc[4][4];
#pragma unroll
  for (int i = 0; i < 4; i++)
#pragma unroll
    for (int j = 0; j < 4; j++) acc[i][j] = f32x4{0.f, 0.f, 0.f, 0.f};

  int r0 = tid >> 2;           // 0..127
  int fslot = tid & 3;
  int row2 = r0 + 128;
  int kgrA0 = fslot ^ ((r0 >> 1) & 3);
  int kgrA1 = fslot ^ ((row2 >> 1) & 3);
  const u16* gA0 = A + (size_t)(bm + r0) * K + kgrA0 * 8;
  const u16* gA1 = A + (size_t)(bm + row2) * K + kgrA1 * 8;
  const u16* gB0 = Wt + (size_t)(bn + r0) * K + kgrA0 * 8;
  int nk = K >> 5;

  gload16(gA0, &lds_a[0][tid * 8]);
  gload16(gA1, &lds_a[0][(tid + 512) * 8]);
  gload16(gB0, &lds_b[0][tid * 8]);
  gload16(gA0 + 32, &lds_a[1][tid * 8]);
  gload16(gA1 + 32, &lds_a[1][(tid + 512) * 8]);
  gload16(gB0 + 32, &lds_b[1][tid * 8]);

  for (int t = 0; t < nk; ++t) {
    int cur = t % 3;
    if (t + 2 < nk) {
      int k0 = (t + 2) << 5;
      int nb = (t + 2) % 3;
      gload16(gA0 + k0, &lds_a[nb][tid * 8]);
      gload16(gA1 + k0, &lds_a[nb][(tid + 512) * 8]);
      gload16(gB0 + k0, &lds_b[nb][tid * 8]);
      asm volatile("s_waitcnt vmcnt(6)" ::: "memory");
    } else if (t + 1 < nk) {
      asm volatile("s_waitcnt vmcnt(3)" ::: "memory");
    } else {
      asm volatile("s_waitcnt vmcnt(0)" ::: "memory");
    }
    __builtin_amdgcn_s_barrier();
    const u16* la = lds_a[cur];
    const u16* lb = lds_b[cur];
    short8 af[4], bfr[4];
#pragma unroll
    for (int mi = 0; mi < 4; mi++) {
      int row = wm + mi * 16 + lr;
      af[mi] = *(const short8*)&la[row * 32 + (kg ^ ((row >> 1) & 3)) * 8];
    }
#pragma unroll
    for (int ni = 0; ni < 4; ni++) {
      int row = wn + ni * 16 + lr;
      bfr[ni] = *(const short8*)&lb[row * 32 + (kg ^ ((row >> 1) & 3)) * 8];
    }
#pragma unroll
    for (int mi = 0; mi < 4; mi++)
#pragma unroll
      for (int ni = 0; ni < 4; ni++)
        acc[mi][ni] = __builtin_amdgcn_mfma_f32_16x16x32_bf16(af[mi], bfr[ni], acc[mi][ni], 0, 0, 0);
    __builtin_amdgcn_s_barrier();
  }

  int seg = 0;
  if (MODE == 5) seg = bn / 384;
  if (MODE == 6) seg = (bn >= 1536) ? 1 : 0;

#pragma unroll
  for (int mi = 0; mi < 4; mi++)
#pragma unroll
    for (int ni = 0; ni < 4; ni++) {
#pragma unroll
      for (int r = 0; r < 4; r++) {
        int gr = bm + wm + mi * 16 + kg * 4 + r;
        int gc = bn + wn + ni * 16 + lr;
        float v = acc[mi][ni][r];
        if (MODE == 3) {
          size_t idx = (size_t)gr * N + gc;
          tokH[idx] = f2bf(bf2f(tokH[idx]) + gamma[gc] * v);
        } else if (MODE == 4) {
          o1[(size_t)gr * N + gc] = f2bf(v);
        } else if (MODE == 5) {
          int col = gc - seg * 384;
          size_t idx = (size_t)gr * 384 + col;
          if (seg == 0) o1[idx] = f2bf(v);
          else if (seg == 1) o2[idx] = f2bf(v);
          else o3[idx] = f2bf(1.0f / (1.0f + __expf(-v)));
        } else if (MODE == 6) {
          if (seg == 0) {
            float tpos = fmaxf(v, 0.0f);
            o1[(size_t)gr * 1536 + gc] = f2bf(tpos * tpos);
          } else {
            o2[(size_t)gr * 384 + (gc - 1536)] = f2bf(1.0f / (1.0f + __expf(-v)));
          }
        }
      }
    }
}

// ---------------- chunked WKV scan (bf16 k/v packed u32, 2 channels/thread) ----------------
__global__ void k_scanA(const u32* __restrict__ k, const u32* __restrict__ v,
                        const float* __restrict__ decay, int dir,
                        float* __restrict__ SP, float* __restrict__ SQ, float* __restrict__ SO) {
  int gid = blockIdx.x * 256 + threadIdx.x;   // over Bn*NCH*192
  int cp = gid % 192;
  int ch = (gid / 192) % NCH;
  int b = gid / (192 * NCH);
  int c = cp * 2;
  float w0 = decay[dir * Cn + c] * (1.0f / Tn);
  float w1 = decay[dir * Cn + c + 1] * (1.0f / Tn);
  size_t be = dir ? ((size_t)b * Tn + ch) * Cn + c : ((size_t)b * Tn + (size_t)ch * LCH) * Cn + c;
  size_t base = be >> 1;
  size_t stride = (dir ? (size_t)Wn * Cn : (size_t)Cn) >> 1;
  const u32* kp = k + base;
  const u32* vp = v + base;
  float p0 = 0.f, q0 = 0.f, o0 = -1e30f, p1 = 0.f, q1 = 0.f, o1 = -1e30f;
  float2 kt = bf2x(kp[0]), vt = bf2x(vp[0]);
  for (int i = 0; i < LCH; i++) {
    float2 kn = {0.f, 0.f}, vn = {0.f, 0.f};
    if (i + 1 < LCH) { kn = bf2x(kp[stride * (i + 1)]); vn = bf2x(vp[stride * (i + 1)]); }
    float no = fmaxf(w0 + o0, kt.x);
    float Aa = __expf(w0 + o0 - no), Bb = __expf(kt.x - no);
    p0 = Aa * p0 + Bb * vt.x; q0 = Aa * q0 + Bb; o0 = no;
    no = fmaxf(w1 + o1, kt.y);
    Aa = __expf(w1 + o1 - no); Bb = __expf(kt.y - no);
    p1 = Aa * p1 + Bb * vt.y; q1 = Aa * q1 + Bb; o1 = no;
    kt = kn; vt = vn;
  }
  size_t sidx = ((size_t)b * NCH + ch) * Cn + c;
  SP[sidx] = p0; SP[sidx + 1] = p1;
  SQ[sidx] = q0; SQ[sidx + 1] = q1;
  SO[sidx] = o0; SO[sidx + 1] = o1;
}

__global__ void k_scanB(const float* __restrict__ decay, int dir,
                        float* __restrict__ SP, float* __restrict__ SQ, float* __restrict__ SO) {
  int gid = blockIdx.x * 256 + threadIdx.x;  // B*C
  int c = gid % Cn, b = gid / Cn;
  float wL = decay[dir * Cn + c] * (1.0f / Tn) * LCH;
  float p = 0.f, q = 0.f, o = -1e30f;
  size_t idx = (size_t)b * NCH * Cn + c;
  float lp = SP[idx], lq = SQ[idx], lo = SO[idx];
  for (int ch = 0; ch < NCH; ch++) {
    float np_ = 0.f, nq_ = 0.f, no_ = 0.f;
    if (ch + 1 < NCH) { np_ = SP[idx + Cn]; nq_ = SQ[idx + Cn]; no_ = SO[idx + Cn]; }
    SP[idx] = p; SQ[idx] = q; SO[idx] = o;
    float o1 = o + wL;
    float no = fmaxf(o1, lo);
    float e1 = __expf(o1 - no), e2 = __expf(lo - no);
    p = p * e1 + lp * e2;
    q = q * e1 + lq * e2;
    o = no;
    lp = np_; lq = nq_; lo = no_;
    idx += Cn;
  }
}

// Phase C: replay chunk. dir0: y -> v (in place). dir1: abf = bf16(r*y) (fused).
__global__ void k_scanC(const u32* __restrict__ k, u32* __restrict__ v,
                        const u32* __restrict__ rh, u32* __restrict__ abf,
                        const float* __restrict__ decay, const float* __restrict__ first, int dir,
                        const float* __restrict__ SP, const float* __restrict__ SQ,
                        const float* __restrict__ SO) {
  int gid = blockIdx.x * 256 + threadIdx.x;
  int cp = gid % 192;
  int ch = (gid / 192) % NCH;
  int b = gid / (192 * NCH);
  int c = cp * 2;
  float w0 = decay[dir * Cn + c] * (1.0f / Tn);
  float w1 = decay[dir * Cn + c + 1] * (1.0f / Tn);
  float u0 = first[dir * Cn + c] * (1.0f / Tn);
  float u1 = first[dir * Cn + c + 1] * (1.0f / Tn);
  size_t be = dir ? ((size_t)b * Tn + ch) * Cn + c : ((size_t)b * Tn + (size_t)ch * LCH) * Cn + c;
  size_t base = be >> 1;
  size_t stride = (dir ? (size_t)Wn * Cn : (size_t)Cn) >> 1;
  const u32* kp = k + base;
  u32* vp = v + base;
  size_t sidx = ((size_t)b * NCH + ch) * Cn + c;
  float p0 = SP[sidx], q0 = SQ[sidx], o0 = SO[sidx];
  float p1 = SP[sidx + 1], q1 = SQ[sidx + 1], o1 = SO[sidx + 1];
  float2 kt = bf2x(kp[0]), vt = bf2x(vp[0]);
  for (int i = 0; i < LCH; i++) {
    float2 kn = {0.f, 0.f}, vn = {0.f, 0.f};
    if (i + 1 < LCH) { kn = bf2x(kp[stride * (i + 1)]); vn = bf2x(vp[stride * (i + 1)]); }
    float no = fmaxf(o0, u0 + kt.x);
    float Aa = __expf(o0 - no), Bb = __expf(u0 + kt.x - no);
    float y0 = (Aa * p0 + Bb * vt.x) / (Aa * q0 + Bb);
    no = fmaxf(o1, u1 + kt.y);
    Aa = __expf(o1 - no); Bb = __expf(u1 + kt.y - no);
    float y1 = (Aa * p1 + Bb * vt.y) / (Aa * q1 + Bb);
    if (dir == 0) {
      vp[stride * i] = f2bx(y0, y1);
    } else {
      size_t idx = base + stride * i;
      float2 rr = bf2x(rh[idx]);
      abf[idx] = f2bx(rr.x * y0, rr.y * y1);
    }
    float no2 = fmaxf(w0 + o0, kt.x);
    float A2 = __expf(w0 + o0 - no2), B2 = __expf(kt.x - no2);
    p0 = A2 * p0 + B2 * vt.x; q0 = A2 * q0 + B2; o0 = no2;
    no2 = fmaxf(w1 + o1, kt.y);
    A2 = __expf(w1 + o1 - no2); B2 = __expf(kt.y - no2);
    p1 = A2 * p1 + B2 * vt.y; q1 = A2 * q1 + B2; o1 = no2;
    kt = kn; vt = vn;
  }
}

// ---------------- final: tok2 = tok1(bf16) + gamma2*(rr*kv), transpose to NCHW fp32 -------
__global__ void k_final(const u16* __restrict__ tok1, const u16* __restrict__ rr,
                        const u16* __restrict__ kv, const float* __restrict__ gamma2,
                        float* __restrict__ out) {
  __shared__ float tile[32][33];
  int b = blockIdx.z, t0 = blockIdx.x * 32, c0 = blockIdx.y * 32;
  int cc = threadIdx.x % 32, tt0 = threadIdx.x / 32;
  size_t base = ((size_t)b * Tn + t0) * Cn + c0;
  float gam = gamma2[c0 + cc];
  for (int i = 0; i < 32; i += 8) {
    size_t idx = base + (size_t)(tt0 + i) * Cn + cc;
    tile[tt0 + i][cc] = bf2f(tok1[idx]) + gam * (bf2f(rr[idx]) * bf2f(kv[idx]));
  }
  __syncthreads();
  int tw = threadIdx.x % 32, cwi = threadIdx.x / 32;
  float* op = out + ((size_t)b * Cn + c0) * Tn + t0;
  for (int i = 0; i < 32; i += 8) op[(size_t)(cwi + i) * Tn + tw] = tile[tw][cwi + i];
}

extern "C" void kernel_launch(void* const* d_in, const int* in_sizes, int n_in, void* d_out,
                              int out_size, void* d_ws, size_t ws_size, hipStream_t stream) {
  const float* x = (const float*)d_in[0];
  const float* ln1_g = (const float*)d_in[1];
  const float* ln1_b = (const float*)d_in[2];
  const float* ln2_g = (const float*)d_in[3];
  const float* ln2_b = (const float*)d_in[4];
  const float* gamma1 = (const float*)d_in[5];
  const float* gamma2 = (const float*)d_in[6];
  const float* att_alpha = (const float*)d_in[7];
  const float* att_w1 = (const float*)d_in[8];
  const float* att_w3 = (const float*)d_in[9];
  const float* att_w5 = (const float*)d_in[10];
  const float* att_wk = (const float*)d_in[11];
  const float* att_wv = (const float*)d_in[12];
  const float* att_wr = (const float*)d_in[13];
  const float* att_wo = (const float*)d_in[14];
  const float* sp_decay = (const float*)d_in[15];
  const float* sp_first = (const float*)d_in[16];
  const float* ffn_alpha = (const float*)d_in[17];
  const float* ffn_w1 = (const float*)d_in[18];
  const float* ffn_w3 = (const float*)d_in[19];
  const float* ffn_w5 = (const float*)d_in[20];
  const float* ffn_wk = (const float*)d_in[21];
  const float* ffn_wv = (const float*)d_in[22];
  const float* ffn_wr = (const float*)d_in[23];
  float* out = (float*)d_out;

  char* ws = (char*)d_ws;
  u16* TOK = (u16*)(ws);
  u16* XS = (u16*)(ws + 24 * MB);
  u16* RRH = (u16*)(ws + 24 * MB);
  u16* ABF = (u16*)(ws + 48 * MB);
  u16* KVO = (u16*)(ws + 48 * MB);
  u16* KBH = (u16*)(ws + 72 * MB);
  u16* KKB = (u16*)(ws + 72 * MB);
  u16* VBH = (u16*)(ws + 96 * MB);
  u16* RBH = (u16*)(ws + 120 * MB);
  char* W0 = ws + 192 * MB;
  const size_t CCB = 294912;       // Cn*Cn*2 bytes
  const size_t CHB = 1179648;      // Cn*HIDn*2 bytes
  u16* wkb = (u16*)(W0);                      // QKV fused: wk|wv|wr contiguous (N=1152)
  u16* wvb = (u16*)(W0 + CCB);
  u16* wrb = (u16*)(W0 + 2 * CCB);
  u16* wob = (u16*)(W0 + 3 * CCB);
  u16* fwkb = (u16*)(W0 + 4 * CCB);           // FFN fused: fwk|fwr contiguous (N=1920)
  u16* fwrb = (u16*)(W0 + 4 * CCB + CHB);
  u16* fwvb = (u16*)(W0 + 4 * CCB + CHB + CCB);
  float* WEFF = (float*)(W0 + 4 * CCB + 2 * CHB + 2 * CCB);
  float* SUMW = WEFF + 2 * Cn * 25;
  float* SP = (float*)((char*)(SUMW + 2 * Cn) + 256);
  float* SQ = SP + NLANE;
  float* SO = SQ + NLANE;

  const int CC = Cn * Cn;            // 147456
  const int CHn = Cn * HIDn;         // 589824
  int prepN = 5 * CC + 2 * CHn + 2 * Cn * 25 + 2 * Cn;
  k_prep<<<(prepN + 255) / 256, 256, 0, stream>>>(
      att_wk, att_wv, att_wr, att_wo, ffn_wk, ffn_wr, ffn_wv,
      att_alpha, att_w1, att_w3, att_w5, ffn_alpha, ffn_w1, ffn_w3, ffn_w5,
      wkb, wvb, wrb, wob, fwkb, fwrb, fwvb, WEFF, SUMW);
  k_transpose_in<<<dim3(Tn / 32, Cn / 32, Bn), 256, 0, stream>>>(x, TOK);

  // ---- attention half ----
  k_lnnorm<<<Mn / 4, 256, 0, stream>>>(TOK, XS);
  dim3 gconv(Hn, Bn);
  k_conv<<<gconv, Cn, 0, stream>>>(XS, ln1_g, ln1_b, WEFF, SUMW, ABF);
  k_gemm<5><<<dim3(Mn / 256, 9), 512, 0, stream>>>(ABF, wkb, KBH, VBH, RBH, nullptr, nullptr,
                                                   Cn, Cn);

  // ---- chunked WKV scans (row then col; col fused with r-multiply into ABF) ----
  int gsc2 = Bn * NCH * 192 / 256;  // 384 blocks
  k_scanA<<<gsc2, 256, 0, stream>>>((u32*)KBH, (u32*)VBH, sp_decay, 0, SP, SQ, SO);
  k_scanB<<<Bn * Cn / 256, 256, 0, stream>>>(sp_decay, 0, SP, SQ, SO);
  k_scanC<<<gsc2, 256, 0, stream>>>((u32*)KBH, (u32*)VBH, nullptr, nullptr, sp_decay, sp_first,
                                    0, SP, SQ, SO);
  k_scanA<<<gsc2, 256, 0, stream>>>((u32*)KBH, (u32*)VBH, sp_decay, 1, SP, SQ, SO);
  k_scanB<<<Bn * Cn / 256, 256, 0, stream>>>(sp_decay, 1, SP, SQ, SO);
  k_scanC<<<gsc2, 256, 0, stream>>>((u32*)KBH, (u32*)VBH, (u32*)RBH, (u32*)ABF, sp_decay,
                                    sp_first, 1, SP, SQ, SO);

  k_gemm<3><<<dim3(Mn / 256, 3), 512, 0, stream>>>(ABF, wob, nullptr, nullptr, nullptr, TOK,
                                                   gamma1, Cn, Cn);

  // ---- FFN half ----
  k_lnnorm<<<Mn / 4, 256, 0, stream>>>(TOK, XS);
  k_conv<<<gconv, Cn, 0, stream>>>(XS, ln2_g, ln2_b, WEFF + 25 * Cn, SUMW + Cn, ABF);
  k_gemm<6><<<dim3(Mn / 256, 15), 512, 0, stream>>>(ABF, fwkb, KKB, RRH, nullptr, nullptr,
                                                    nullptr, Cn, Cn);
  k_gemm<4><<<dim3(Mn / 256, 3), 512, 0, stream>>>(KKB, fwvb, KVO, nullptr, nullptr, nullptr,
                                                   nullptr, HIDn, Cn);
  k_final<<<dim3(Tn / 32, Cn / 32, Bn), 256, 0, stream>>>(TOK, RRH, KVO, gamma2, out);
}

// Round 19
// 458.241 us; speedup vs baseline: 1.2514x; 1.0254x over previous
//
#include <hip/hip_runtime.h>

typedef unsigned short u16;
typedef unsigned int u32;
typedef __attribute__((ext_vector_type(8))) short short8;
typedef __attribute__((ext_vector_type(4))) float f32x4;

constexpr int Bn = 8, Cn = 384, Hn = 64, Wn = 64, Tn = Hn * Wn, Mn = Bn * Tn, HIDn = 1536;
constexpr size_t MB = 1024 * 1024;
constexpr int NCH = 64, LCH = Tn / NCH;      // 64 chunks x 64 steps
constexpr int NLANE = Bn * NCH * Cn;         // state lanes (per channel)
constexpr int CV = 8;                        // conv outputs per chunk (along w)

__device__ __forceinline__ u16 f2bf(float f) {
  unsigned u = __builtin_bit_cast(unsigned, f);
  unsigned r = (u + 0x7fffu + ((u >> 16) & 1u)) >> 16;
  return (u16)r;
}

__device__ __forceinline__ float bf2f(u16 h) {
  return __builtin_bit_cast(float, (unsigned)h << 16);
}

__device__ __forceinline__ float2 bf2x(u32 w) {
  float2 r;
  r.x = bf2f((u16)(w & 0xffffu));
  r.y = bf2f((u16)(w >> 16));
  return r;
}

__device__ __forceinline__ u32 f2bx(float a, float b) {
  return (u32)f2bf(a) | ((u32)f2bf(b) << 16);
}

__device__ __forceinline__ void gload16(const u16* g, u16* l) {
  __builtin_amdgcn_global_load_lds(
      (const __attribute__((address_space(1))) unsigned int*)(g),
      (__attribute__((address_space(3))) unsigned int*)(l), 16, 0, 0);
}

// ---------------- transpose x [B,C,T] fp32 -> tok [B,T,C] bf16 ----------------
__global__ void k_transpose_in(const float* __restrict__ x, u16* __restrict__ tok) {
  __shared__ float tile[32][33];
  int b = blockIdx.z, t0 = blockIdx.x * 32, c0 = blockIdx.y * 32;
  int tt = threadIdx.x % 32, cc = threadIdx.x / 32;
  const float* xp = x + ((size_t)b * Cn + c0) * Tn + t0;
  for (int i = 0; i < 32; i += 8) tile[cc + i][tt] = xp[(size_t)(cc + i) * Tn + tt];
  __syncthreads();
  int cw = threadIdx.x % 32, tw = threadIdx.x / 32;
  u16* op = tok + ((size_t)b * Tn + t0) * Cn + c0;
  for (int i = 0; i < 32; i += 8) op[(size_t)(tw + i) * Cn + cw] = f2bf(tile[cw][tw + i]);
}

// ---------------- one-shot weight prep: bf16 converts + effective 5x5 + sumw -------------
__global__ void k_prep(const float* __restrict__ wk, const float* __restrict__ wv,
                       const float* __restrict__ wr, const float* __restrict__ wo,
                       const float* __restrict__ fwk, const float* __restrict__ fwr,
                       const float* __restrict__ fwv,
                       const float* __restrict__ aA, const float* __restrict__ w1A,
                       const float* __restrict__ w3A, const float* __restrict__ w5A,
                       const float* __restrict__ aF, const float* __restrict__ w1F,
                       const float* __restrict__ w3F, const float* __restrict__ w5F,
                       u16* __restrict__ wkb, u16* __restrict__ wvb, u16* __restrict__ wrb,
                       u16* __restrict__ wob, u16* __restrict__ fwkb, u16* __restrict__ fwrb,
                       u16* __restrict__ fwvb, float* __restrict__ weff,
                       float* __restrict__ sumw) {
  const int CC = Cn * Cn, CH = Cn * HIDn;
  int i = blockIdx.x * 256 + threadIdx.x;
  if (i < 4 * CC) {
    int seg = i / CC, j = i % CC;
    if (seg == 0) wkb[j] = f2bf(wk[j]);
    else if (seg == 1) wvb[j] = f2bf(wv[j]);
    else if (seg == 2) wrb[j] = f2bf(wr[j]);
    else wob[j] = f2bf(wo[j]);
    return;
  }
  i -= 4 * CC;
  if (i < CH) { fwkb[i] = f2bf(fwk[i]); return; }
  i -= CH;
  if (i < CC) { fwrb[i] = f2bf(fwr[i]); return; }
  i -= CC;
  if (i < CH) { fwvb[i] = f2bf(fwv[i]); return; }
  i -= CH;
  if (i < 2 * Cn * 25) {
    int set = i / (Cn * 25), rem = i % (Cn * 25), c = rem / 25, ij = rem % 25;
    int ki = ij / 5, kj = ij % 5;
    const float* a = set ? aF : aA;
    const float* w1 = set ? w1F : w1A;
    const float* w3 = set ? w3F : w3A;
    const float* w5 = set ? w5F : w5A;
    float v = a[3] * w5[c * 25 + ij];
    if (ki >= 1 && ki <= 3 && kj >= 1 && kj <= 3) v += a[2] * w3[c * 9 + (ki - 1) * 3 + (kj - 1)];
    if (ki == 2 && kj == 2) v += a[1] * w1[c] + a[0];
    weff[(set * 25 + ij) * Cn + c] = v;
    return;
  }
  i -= 2 * Cn * 25;
  if (i < 2 * Cn) {
    int set = i / Cn, c = i % Cn;
    const float* a = set ? aF : aA;
    const float* w1 = set ? w1F : w1A;
    const float* w3 = set ? w3F : w3A;
    const float* w5 = set ? w5F : w5A;
    float s = 0.f;
    for (int ij = 0; ij < 25; ij++) {
      int ki = ij / 5, kj = ij % 5;
      float v = a[3] * w5[c * 25 + ij];
      if (ki >= 1 && ki <= 3 && kj >= 1 && kj <= 3)
        v += a[2] * w3[c * 9 + (ki - 1) * 3 + (kj - 1)];
      if (ki == 2 && kj == 2) v += a[1] * w1[c] + a[0];
      s += v;
    }
    sumw[i] = s;
  }
}

// ---------------- fused LN: stats + write normalized x as bf16 (bf16 in) ----------------
__global__ void k_lnnorm(const u16* __restrict__ tok, u16* __restrict__ xs) {
  int token = blockIdx.x * 4 + (threadIdx.x >> 6);
  int lane = threadIdx.x & 63;
  const u32* p = (const u32*)(tok + (size_t)token * Cn);
  float v[6];
  float s = 0.f, s2 = 0.f;
#pragma unroll
  for (int j = 0; j < 3; j++) {
    float2 f = bf2x(p[lane + j * 64]);
    v[2 * j] = f.x; v[2 * j + 1] = f.y;
    s += f.x + f.y;
    s2 += f.x * f.x + f.y * f.y;
  }
  for (int off = 32; off; off >>= 1) { s += __shfl_xor(s, off); s2 += __shfl_xor(s2, off); }
  float m = s * (1.0f / Cn);
  float r = rsqrtf(s2 * (1.0f / Cn) - m * m + 1e-5f);
  u32* op = (u32*)(xs + (size_t)token * Cn);
#pragma unroll
  for (int j = 0; j < 3; j++)
    op[lane + j * 64] = f2bx((v[2 * j] - m) * r, (v[2 * j + 1] - m) * r);
}

// ---------------- 5x5 depthwise conv on normalized x (bf16 in/out) ----------------
__global__ __launch_bounds__(384) void k_conv(const u16* __restrict__ xs,
                                              const float* __restrict__ g,
                                              const float* __restrict__ bb,
                                              const float* __restrict__ weff,
                                              const float* __restrict__ sumw,
                                              u16* __restrict__ out) {
  int c = threadIdx.x;
  int h = blockIdx.x, b = blockIdx.y;
  float gc = g[c], bc = bb[c], s0 = sumw[c];
  float wv[25];
#pragma unroll
  for (int i = 0; i < 25; i++) wv[i] = weff[i * Cn + c];
  const u16* base = xs + (size_t)b * Tn * Cn + c;
  u16* orow = out + ((size_t)b * Tn + (size_t)h * Wn) * Cn + c;
  bool hOK = (h >= 2 && h <= Hn - 3);
  for (int w0 = 0; w0 < Wn; w0 += CV) {
    float acc[CV];
#pragma unroll
    for (int v = 0; v < CV; v++) acc[v] = 0.f;
    if (hOK && w0 != 0 && w0 != Wn - CV) {
#pragma unroll
      for (int ki = 0; ki < 5; ki++) {
        int rowt = (h + ki - 2) * Wn + w0 - 2;
#pragma unroll
        for (int jj = 0; jj < CV + 4; jj++) {
          float y = bf2f(base[(size_t)(rowt + jj) * Cn]);
#pragma unroll
          for (int v = 0; v < CV; v++) {
            int kj = jj - v;
            if (kj >= 0 && kj < 5) acc[v] = fmaf(y, wv[ki * 5 + kj], acc[v]);
          }
        }
      }
      u16* op = orow + (size_t)w0 * Cn;
#pragma unroll
      for (int v = 0; v < CV; v++) op[(size_t)v * Cn] = f2bf(gc * acc[v] + bc * s0);
    } else {
      float sw[CV];
#pragma unroll
      for (int v = 0; v < CV; v++) sw[v] = 0.f;
#pragma unroll
      for (int ki = 0; ki < 5; ki++) {
        int hh = h + ki - 2;
        if ((unsigned)hh >= (unsigned)Hn) continue;
#pragma unroll
        for (int jj = 0; jj < CV + 4; jj++) {
          int ww = w0 + jj - 2;
          if ((unsigned)ww >= (unsigned)Wn) continue;
          float y = bf2f(base[(size_t)(hh * Wn + ww) * Cn]);
#pragma unroll
          for (int v = 0; v < CV; v++) {
            int kj = jj - v;
            if (kj >= 0 && kj < 5) {
              float wt = wv[ki * 5 + kj];
              acc[v] = fmaf(y, wt, acc[v]);
              sw[v] += wt;
            }
          }
        }
      }
      u16* op = orow + (size_t)w0 * Cn;
#pragma unroll
      for (int v = 0; v < CV; v++) op[(size_t)v * Cn] = f2bf(gc * acc[v] + bc * sw[v]);
    }
  }
}

// ---- bf16 GEMM: 256x128 tile, 512 thr, BK=32, XOR swizzle, N-inner XCD remap ----
// 3-buffer counted-vmcnt pipeline; LDS-repacked coalesced C-write (MODES 4/5/6).
// MODE 3: tokH += gamma*val (bf16 in place, stride N; scattered RMW path)
// MODE 4: plain bf16 -> o1 (stride N)
// MODE 5: fused QKV: seg0->o1, seg1->o2, seg2->sigmoid->o3 (each stride 384)
// MODE 6: fused FFN: seg0->relu^2->o1 (stride 1536), seg1->sigmoid->o2 (stride 384)
template <int MODE>
__global__ __launch_bounds__(512) void k_gemm(const u16* __restrict__ A,
                                              const u16* __restrict__ Wt,
                                              u16* __restrict__ o1, u16* __restrict__ o2,
                                              u16* __restrict__ o3,
                                              u16* __restrict__ tokH,
                                              const float* __restrict__ gamma, int K, int N) {
  __shared__ u16 smem[36864];          // 72 KB: staging (3x8192 A + 3x4096 B) / C-tile reuse
  u16* lds_a = smem;                   // bufs at +0, +8192, +16384
  u16* lds_b = smem + 24576;           // bufs at +0, +4096, +8192
  int tid = threadIdx.x;
  int id = blockIdx.y * gridDim.x + blockIdx.x;
  int xcd = id & 7, q = id >> 3;
  int nN = gridDim.y;
  int bn = (q % nN) * 128;
  int bm = ((q / nN) * 8 + xcd) * 256;   // N-inner: all N for one M-panel per XCD
  int wave = tid >> 6, lane = tid & 63;
  int wm = (wave >> 1) * 64, wn = (wave & 1) * 64;
  int lr = lane & 15, kg = lane >> 4;

  f32x4 acc[4][4];
#pragma unroll
  for (int i = 0; i < 4; i++)
#pragma unroll
    for (int j = 0; j < 4; j++) acc[i][j] = f32x4{0.f, 0.f, 0.f, 0.f};

  int r0 = tid >> 2;           // 0..127
  int fslot = tid & 3;
  int row2 = r0 + 128;
  int kgrA0 = fslot ^ ((r0 >> 1) & 3);
  int kgrA1 = fslot ^ ((row2 >> 1) & 3);
  const u16* gA0 = A + (size_t)(bm + r0) * K + kgrA0 * 8;
  const u16* gA1 = A + (size_t)(bm + row2) * K + kgrA1 * 8;
  const u16* gB0 = Wt + (size_t)(bn + r0) * K + kgrA0 * 8;
  int nk = K >> 5;

  gload16(gA0, lds_a + tid * 8);
  gload16(gA1, lds_a + (tid + 512) * 8);
  gload16(gB0, lds_b + tid * 8);
  gload16(gA0 + 32, lds_a + 8192 + tid * 8);
  gload16(gA1 + 32, lds_a + 8192 + (tid + 512) * 8);
  gload16(gB0 + 32, lds_b + 4096 + tid * 8);

  for (int t = 0; t < nk; ++t) {
    int cur = t % 3;
    if (t + 2 < nk) {
      int k0 = (t + 2) << 5;
      int nb = (t + 2) % 3;
      gload16(gA0 + k0, lds_a + nb * 8192 + tid * 8);
      gload16(gA1 + k0, lds_a + nb * 8192 + (tid + 512) * 8);
      gload16(gB0 + k0, lds_b + nb * 4096 + tid * 8);
      asm volatile("s_waitcnt vmcnt(6)" ::: "memory");
    } else if (t + 1 < nk) {
      asm volatile("s_waitcnt vmcnt(3)" ::: "memory");
    } else {
      asm volatile("s_waitcnt vmcnt(0)" ::: "memory");
    }
    __builtin_amdgcn_s_barrier();
    const u16* la = lds_a + cur * 8192;
    const u16* lb = lds_b + cur * 4096;
    short8 af[4], bfr[4];
#pragma unroll
    for (int mi = 0; mi < 4; mi++) {
      int row = wm + mi * 16 + lr;
      af[mi] = *(const short8*)&la[row * 32 + (kg ^ ((row >> 1) & 3)) * 8];
    }
#pragma unroll
    for (int ni = 0; ni < 4; ni++) {
      int row = wn + ni * 16 + lr;
      bfr[ni] = *(const short8*)&lb[row * 32 + (kg ^ ((row >> 1) & 3)) * 8];
    }
#pragma unroll
    for (int mi = 0; mi < 4; mi++)
#pragma unroll
      for (int ni = 0; ni < 4; ni++)
        acc[mi][ni] = __builtin_amdgcn_mfma_f32_16x16x32_bf16(af[mi], bfr[ni], acc[mi][ni], 0, 0, 0);
    __builtin_amdgcn_s_barrier();
  }

  int seg = 0;
  if (MODE == 5) seg = bn / 384;
  if (MODE == 6) seg = (bn >= 1536) ? 1 : 0;

  if (MODE == 3) {
#pragma unroll
    for (int mi = 0; mi < 4; mi++)
#pragma unroll
      for (int ni = 0; ni < 4; ni++) {
#pragma unroll
        for (int r = 0; r < 4; r++) {
          int gr = bm + wm + mi * 16 + kg * 4 + r;
          int gc = bn + wn + ni * 16 + lr;
          size_t idx = (size_t)gr * N + gc;
          tokH[idx] = f2bf(bf2f(tokH[idx]) + gamma[gc] * acc[mi][ni][r]);
        }
      }
  } else {
    // repack C tile via LDS for fully-coalesced 16B stores
    u16* lds_c = smem;   // 256*128 u16 = 64 KB (staging dead after final barrier)
#pragma unroll
    for (int mi = 0; mi < 4; mi++)
#pragma unroll
      for (int ni = 0; ni < 4; ni++) {
        int colL = wn + ni * 16 + lr;
#pragma unroll
        for (int r = 0; r < 4; r++) {
          int row = wm + mi * 16 + kg * 4 + r;
          float v = acc[mi][ni][r];
          u16 hv;
          if (MODE == 4) {
            hv = f2bf(v);
          } else if (MODE == 5) {
            hv = (seg == 2) ? f2bf(1.0f / (1.0f + __expf(-v))) : f2bf(v);
          } else {  // MODE 6
            if (seg == 0) {
              float tpos = fmaxf(v, 0.0f);
              hv = f2bf(tpos * tpos);
            } else {
              hv = f2bf(1.0f / (1.0f + __expf(-v)));
            }
          }
          lds_c[row * 128 + colL] = hv;
        }
      }
    __syncthreads();
    u16* P;
    int S, cb;
    if (MODE == 4) { P = o1; S = N; cb = bn; }
    else if (MODE == 5) {
      P = (seg == 0) ? o1 : (seg == 1) ? o2 : o3;
      S = 384; cb = bn - seg * 384;
    } else {
      if (seg == 0) { P = o1; S = 1536; cb = bn; }
      else { P = o2; S = 384; cb = bn - 1536; }
    }
#pragma unroll
    for (int it = 0; it < 8; ++it) {
      int l = (tid + it * 512) * 8;
      int row = l >> 7, col = l & 127;
      *(short8*)(P + (size_t)(bm + row) * S + cb + col) = *(const short8*)(lds_c + l);
    }
  }
}

// ---------------- chunked WKV scan (bf16 k/v packed u32, 2 channels/thread) ----------------
__global__ void k_scanA(const u32* __restrict__ k, const u32* __restrict__ v,
                        const float* __restrict__ decay, int dir,
                        float* __restrict__ SP, float* __restrict__ SQ, float* __restrict__ SO) {
  int gid = blockIdx.x * 256 + threadIdx.x;   // over Bn*NCH*192
  int cp = gid % 192;
  int ch = (gid / 192) % NCH;
  int b = gid / (192 * NCH);
  int c = cp * 2;
  float w0 = decay[dir * Cn + c] * (1.0f / Tn);
  float w1 = decay[dir * Cn + c + 1] * (1.0f / Tn);
  size_t be = dir ? ((size_t)b * Tn + ch) * Cn + c : ((size_t)b * Tn + (size_t)ch * LCH) * Cn + c;
  size_t base = be >> 1;
  size_t stride = (dir ? (size_t)Wn * Cn : (size_t)Cn) >> 1;
  const u32* kp = k + base;
  const u32* vp = v + base;
  float p0 = 0.f, q0 = 0.f, o0 = -1e30f, p1 = 0.f, q1 = 0.f, o1 = -1e30f;
  float2 kt = bf2x(kp[0]), vt = bf2x(vp[0]);
  for (int i = 0; i < LCH; i++) {
    float2 kn = {0.f, 0.f}, vn = {0.f, 0.f};
    if (i + 1 < LCH) { kn = bf2x(kp[stride * (i + 1)]); vn = bf2x(vp[stride * (i + 1)]); }
    float no = fmaxf(w0 + o0, kt.x);
    float Aa = __expf(w0 + o0 - no), Bb = __expf(kt.x - no);
    p0 = Aa * p0 + Bb * vt.x; q0 = Aa * q0 + Bb; o0 = no;
    no = fmaxf(w1 + o1, kt.y);
    Aa = __expf(w1 + o1 - no); Bb = __expf(kt.y - no);
    p1 = Aa * p1 + Bb * vt.y; q1 = Aa * q1 + Bb; o1 = no;
    kt = kn; vt = vn;
  }
  size_t sidx = ((size_t)b * NCH + ch) * Cn + c;
  SP[sidx] = p0; SP[sidx + 1] = p1;
  SQ[sidx] = q0; SQ[sidx + 1] = q1;
  SO[sidx] = o0; SO[sidx + 1] = o1;
}

// Phase C: in-thread exclusive prefix over chunk states (replaces scanB), then replay.
// dir0: y -> v (in place). dir1: abf = bf16(r*y) (fused).
__global__ void k_scanC(const u32* __restrict__ k, u32* __restrict__ v,
                        const u32* __restrict__ rh, u32* __restrict__ abf,
                        const float* __restrict__ decay, const float* __restrict__ first, int dir,
                        const float* __restrict__ SP, const float* __restrict__ SQ,
                        const float* __restrict__ SO) {
  int gid = blockIdx.x * 256 + threadIdx.x;
  int cp = gid % 192;
  int ch = (gid / 192) % NCH;
  int b = gid / (192 * NCH);
  int c = cp * 2;
  float w0 = decay[dir * Cn + c] * (1.0f / Tn);
  float w1 = decay[dir * Cn + c + 1] * (1.0f / Tn);
  float u0 = first[dir * Cn + c] * (1.0f / Tn);
  float u1 = first[dir * Cn + c + 1] * (1.0f / Tn);
  float wL0 = w0 * LCH, wL1 = w1 * LCH;
  // exclusive prefix combine over chunks 0..ch-1 (same order as old scanB)
  float p0 = 0.f, q0 = 0.f, o0 = -1e30f, p1 = 0.f, q1 = 0.f, o1 = -1e30f;
  size_t sj = (size_t)b * NCH * Cn + c;
  for (int j = 0; j < ch; ++j, sj += Cn) {
    float lp0 = SP[sj], lq0 = SQ[sj], lo0 = SO[sj];
    float lp1 = SP[sj + 1], lq1 = SQ[sj + 1], lo1 = SO[sj + 1];
    float oo = o0 + wL0;
    float no = fmaxf(oo, lo0);
    float e1 = __expf(oo - no), e2 = __expf(lo0 - no);
    p0 = p0 * e1 + lp0 * e2; q0 = q0 * e1 + lq0 * e2; o0 = no;
    oo = o1 + wL1;
    no = fmaxf(oo, lo1);
    e1 = __expf(oo - no); e2 = __expf(lo1 - no);
    p1 = p1 * e1 + lp1 * e2; q1 = q1 * e1 + lq1 * e2; o1 = no;
  }
  size_t be = dir ? ((size_t)b * Tn + ch) * Cn + c : ((size_t)b * Tn + (size_t)ch * LCH) * Cn + c;
  size_t base = be >> 1;
  size_t stride = (dir ? (size_t)Wn * Cn : (size_t)Cn) >> 1;
  const u32* kp = k + base;
  u32* vp = v + base;
  float2 kt = bf2x(kp[0]), vt = bf2x(vp[0]);
  for (int i = 0; i < LCH; i++) {
    float2 kn = {0.f, 0.f}, vn = {0.f, 0.f};
    if (i + 1 < LCH) { kn = bf2x(kp[stride * (i + 1)]); vn = bf2x(vp[stride * (i + 1)]); }
    float no = fmaxf(o0, u0 + kt.x);
    float Aa = __expf(o0 - no), Bb = __expf(u0 + kt.x - no);
    float y0 = (Aa * p0 + Bb * vt.x) / (Aa * q0 + Bb);
    no = fmaxf(o1, u1 + kt.y);
    Aa = __expf(o1 - no); Bb = __expf(u1 + kt.y - no);
    float y1 = (Aa * p1 + Bb * vt.y) / (Aa * q1 + Bb);
    if (dir == 0) {
      vp[stride * i] = f2bx(y0, y1);
    } else {
      size_t idx = base + stride * i;
      float2 rr = bf2x(rh[idx]);
      abf[idx] = f2bx(rr.x * y0, rr.y * y1);
    }
    float no2 = fmaxf(w0 + o0, kt.x);
    float A2 = __expf(w0 + o0 - no2), B2 = __expf(kt.x - no2);
    p0 = A2 * p0 + B2 * vt.x; q0 = A2 * q0 + B2; o0 = no2;
    no2 = fmaxf(w1 + o1, kt.y);
    A2 = __expf(w1 + o1 - no2); B2 = __expf(kt.y - no2);
    p1 = A2 * p1 + B2 * vt.y; q1 = A2 * q1 + B2; o1 = no2;
    kt = kn; vt = vn;
  }
}

// ---------------- final: tok2 = tok1(bf16) + gamma2*(rr*kv), transpose to NCHW fp32 -------
__global__ void k_final(const u16* __restrict__ tok1, const u16* __restrict__ rr,
                        const u16* __restrict__ kv, const float* __restrict__ gamma2,
                        float* __restrict__ out) {
  __shared__ float tile[32][33];
  int b = blockIdx.z, t0 = blockIdx.x * 32, c0 = blockIdx.y * 32;
  int cc = threadIdx.x % 32, tt0 = threadIdx.x / 32;
  size_t base = ((size_t)b * Tn + t0) * Cn + c0;
  float gam = gamma2[c0 + cc];
  for (int i = 0; i < 32; i += 8) {
    size_t idx = base + (size_t)(tt0 + i) * Cn + cc;
    tile[tt0 + i][cc] = bf2f(tok1[idx]) + gam * (bf2f(rr[idx]) * bf2f(kv[idx]));
  }
  __syncthreads();
  int tw = threadIdx.x % 32, cwi = threadIdx.x / 32;
  float* op = out + ((size_t)b * Cn + c0) * Tn + t0;
  for (int i = 0; i < 32; i += 8) op[(size_t)(cwi + i) * Tn + tw] = tile[tw][cwi + i];
}

extern "C" void kernel_launch(void* const* d_in, const int* in_sizes, int n_in, void* d_out,
                              int out_size, void* d_ws, size_t ws_size, hipStream_t stream) {
  const float* x = (const float*)d_in[0];
  const float* ln1_g = (const float*)d_in[1];
  const float* ln1_b = (const float*)d_in[2];
  const float* ln2_g = (const float*)d_in[3];
  const float* ln2_b = (const float*)d_in[4];
  const float* gamma1 = (const float*)d_in[5];
  const float* gamma2 = (const float*)d_in[6];
  const float* att_alpha = (const float*)d_in[7];
  const float* att_w1 = (const float*)d_in[8];
  const float* att_w3 = (const float*)d_in[9];
  const float* att_w5 = (const float*)d_in[10];
  const float* att_wk = (const float*)d_in[11];
  const float* att_wv = (const float*)d_in[12];
  const float* att_wr = (const float*)d_in[13];
  const float* att_wo = (const float*)d_in[14];
  const float* sp_decay = (const float*)d_in[15];
  const float* sp_first = (const float*)d_in[16];
  const float* ffn_alpha = (const float*)d_in[17];
  const float* ffn_w1 = (const float*)d_in[18];
  const float* ffn_w3 = (const float*)d_in[19];
  const float* ffn_w5 = (const float*)d_in[20];
  const float* ffn_wk = (const float*)d_in[21];
  const float* ffn_wv = (const float*)d_in[22];
  const float* ffn_wr = (const float*)d_in[23];
  float* out = (float*)d_out;

  char* ws = (char*)d_ws;
  u16* TOK = (u16*)(ws);
  u16* XS = (u16*)(ws + 24 * MB);
  u16* RRH = (u16*)(ws + 24 * MB);
  u16* ABF = (u16*)(ws + 48 * MB);
  u16* KVO = (u16*)(ws + 48 * MB);
  u16* KBH = (u16*)(ws + 72 * MB);
  u16* KKB = (u16*)(ws + 72 * MB);
  u16* VBH = (u16*)(ws + 96 * MB);
  u16* RBH = (u16*)(ws + 120 * MB);
  char* W0 = ws + 192 * MB;
  const size_t CCB = 294912;       // Cn*Cn*2 bytes
  const size_t CHB = 1179648;      // Cn*HIDn*2 bytes
  u16* wkb = (u16*)(W0);                      // QKV fused: wk|wv|wr contiguous (N=1152)
  u16* wvb = (u16*)(W0 + CCB);
  u16* wrb = (u16*)(W0 + 2 * CCB);
  u16* wob = (u16*)(W0 + 3 * CCB);
  u16* fwkb = (u16*)(W0 + 4 * CCB);           // FFN fused: fwk|fwr contiguous (N=1920)
  u16* fwrb = (u16*)(W0 + 4 * CCB + CHB);
  u16* fwvb = (u16*)(W0 + 4 * CCB + CHB + CCB);
  float* WEFF = (float*)(W0 + 4 * CCB + 2 * CHB + 2 * CCB);
  float* SUMW = WEFF + 2 * Cn * 25;
  float* SP = (float*)((char*)(SUMW + 2 * Cn) + 256);
  float* SQ = SP + NLANE;
  float* SO = SQ + NLANE;

  const int CC = Cn * Cn;            // 147456
  const int CHn = Cn * HIDn;         // 589824
  int prepN = 5 * CC + 2 * CHn + 2 * Cn * 25 + 2 * Cn;
  k_prep<<<(prepN + 255) / 256, 256, 0, stream>>>(
      att_wk, att_wv, att_wr, att_wo, ffn_wk, ffn_wr, ffn_wv,
      att_alpha, att_w1, att_w3, att_w5, ffn_alpha, ffn_w1, ffn_w3, ffn_w5,
      wkb, wvb, wrb, wob, fwkb, fwrb, fwvb, WEFF, SUMW);
  k_transpose_in<<<dim3(Tn / 32, Cn / 32, Bn), 256, 0, stream>>>(x, TOK);

  // ---- attention half ----
  k_lnnorm<<<Mn / 4, 256, 0, stream>>>(TOK, XS);
  dim3 gconv(Hn, Bn);
  k_conv<<<gconv, Cn, 0, stream>>>(XS, ln1_g, ln1_b, WEFF, SUMW, ABF);
  k_gemm<5><<<dim3(Mn / 256, 9), 512, 0, stream>>>(ABF, wkb, KBH, VBH, RBH, nullptr, nullptr,
                                                   Cn, Cn);

  // ---- chunked WKV scans (A: local states, C: prefix+replay; B folded into C) ----
  int gsc2 = Bn * NCH * 192 / 256;  // 384 blocks
  k_scanA<<<gsc2, 256, 0, stream>>>((u32*)KBH, (u32*)VBH, sp_decay, 0, SP, SQ, SO);
  k_scanC<<<gsc2, 256, 0, stream>>>((u32*)KBH, (u32*)VBH, nullptr, nullptr, sp_decay, sp_first,
                                    0, SP, SQ, SO);
  k_scanA<<<gsc2, 256, 0, stream>>>((u32*)KBH, (u32*)VBH, sp_decay, 1, SP, SQ, SO);
  k_scanC<<<gsc2, 256, 0, stream>>>((u32*)KBH, (u32*)VBH, (u32*)RBH, (u32*)ABF, sp_decay,
                                    sp_first, 1, SP, SQ, SO);

  k_gemm<3><<<dim3(Mn / 256, 3), 512, 0, stream>>>(ABF, wob, nullptr, nullptr, nullptr, TOK,
                                                   gamma1, Cn, Cn);

  // ---- FFN half ----
  k_lnnorm<<<Mn / 4, 256, 0, stream>>>(TOK, XS);
  k_conv<<<gconv, Cn, 0, stream>>>(XS, ln2_g, ln2_b, WEFF + 25 * Cn, SUMW + Cn, ABF);
  k_gemm<6><<<dim3(Mn / 256, 15), 512, 0, stream>>>(ABF, fwkb, KKB, RRH, nullptr, nullptr,
                                                    nullptr, Cn, Cn);
  k_gemm<4><<<dim3(Mn / 256, 3), 512, 0, stream>>>(KKB, fwvb, KVO, nullptr, nullptr, nullptr,
                                                   nullptr, HIDn, Cn);
  k_final<<<dim3(Tn / 32, Cn / 32, Bn), 256, 0, stream>>>(TOK, RRH, KVO, gamma2, out);
}